// Round 4
// baseline (714.493 us; speedup 1.0000x reference)
//
#include <hip/hip_runtime.h>

// ---------------------------------------------------------------------------
// RGAT encoder: N=50000, E=800000, R=8, IN=H=128, B=10.
// R12: fuse pooling + output GEMM, eliminating the g[N][8][128] round-trip
//      (R11: 100 MB write + 102 MB read, k_gather latency-bound at 73us).
//      Per layer: k_score (stbl = x@Wqk, bf16 cast) -> k_weights (softmax per
//      target, writes per-edge {src,w} int2) -> k_fused (per wave: 16 targets;
//      per relation r: pool (t,r) edge runs into own LDS As rows, then
//      MFMA As @ W_r (B-frags straight from L2), accumulate over r; epilogue
//      bias+relu -> h). Waves fully independent: NO barriers, pooling latency
//      of one wave overlaps MFMA of others. CSR on (t,r) segments as R11.
// ---------------------------------------------------------------------------

typedef unsigned int uint;
typedef unsigned short ushort_t;

using bf16x8 = __attribute__((ext_vector_type(8))) __bf16;
using f32x4  = __attribute__((ext_vector_type(4))) float;

__device__ __forceinline__ ushort_t fToBf(float f) {
  uint u = __float_as_uint(f);
  u += 0x7FFFu + ((u >> 16) & 1);   // round-to-nearest-even
  return (ushort_t)(u >> 16);
}
__device__ __forceinline__ float bfToF(ushort_t h) {
  return __uint_as_float(((uint)h) << 16);
}
__device__ __forceinline__ uint packBf(float a, float b) {
  return (uint)fToBf(a) | ((uint)fToBf(b) << 16);
}

// ------------------------------- CSR build ---------------------------------
// Segments keyed on t8r = tgt*8 + rel (400k segments). Within a target the
// 8 relation runs are contiguous and ascending; softmax segment = [t*8, t*8+8).

__global__ void k_count2(const int* __restrict__ tgt, const int* __restrict__ et,
                         int* __restrict__ deg2, int E) {
  int e = blockIdx.x * 256 + threadIdx.x;
  if (e < E) atomicAdd(&deg2[tgt[e] * 8 + et[e]], 1);
}

__global__ void k_scanA(const int* __restrict__ deg, int* __restrict__ incl,
                        int* __restrict__ bsum, int n) {
  __shared__ int s[256];
  int tid = threadIdx.x;
  int i = blockIdx.x * 256 + tid;
  int v = (i < n) ? deg[i] : 0;
  s[tid] = v;
  __syncthreads();
  for (int off = 1; off < 256; off <<= 1) {
    int t = (tid >= off) ? s[tid - off] : 0;
    __syncthreads();
    s[tid] += t;
    __syncthreads();
  }
  if (i < n) incl[i] = s[tid];
  if (tid == 255) bsum[blockIdx.x] = s[255];
}

// single-block chunked exclusive scan of bsum[nb]
__global__ void k_scanB2(int* __restrict__ bsum, int nb) {
  __shared__ int s[256];
  __shared__ int carry;
  int tid = threadIdx.x;
  if (tid == 0) carry = 0;
  __syncthreads();
  for (int base = 0; base < nb; base += 256) {
    int i = base + tid;
    int v = (i < nb) ? bsum[i] : 0;
    s[tid] = v;
    __syncthreads();
    for (int off = 1; off < 256; off <<= 1) {
      int t = (tid >= off) ? s[tid - off] : 0;
      __syncthreads();
      s[tid] += t;
      __syncthreads();
    }
    int c = carry;
    if (i < nb) bsum[i] = c + s[tid] - v;   // exclusive
    __syncthreads();
    if (tid == 255) carry = c + s[255];
    __syncthreads();
  }
}

__global__ void k_scanC(const int* __restrict__ deg, const int* __restrict__ incl,
                        const int* __restrict__ bsum, int* __restrict__ rowptr,
                        int n, int E) {
  int i = blockIdx.x * 256 + threadIdx.x;
  if (i < n) {
    rowptr[i] = bsum[blockIdx.x] + incl[i] - deg[i];
    if (i == n - 1) rowptr[n] = E;
  }
}

__global__ void k_scatter2(const int* __restrict__ src, const int* __restrict__ tgt,
                           const int* __restrict__ et, const int* __restrict__ rowptr2,
                           int* __restrict__ cursor2, int* __restrict__ sorted, int E) {
  int e = blockIdx.x * 256 + threadIdx.x;
  if (e >= E) return;
  int t8r = tgt[e] * 8 + et[e];
  int pos = atomicAdd(&cursor2[t8r], 1);
  sorted[rowptr2[t8r] + pos] = src[e] | (et[e] << 16);   // src < 65536, rel < 8
}

// ------------------------------ weight prep --------------------------------
// WsT[layer][r][n=128][k=128] bf16, value = W[r][k][n]: direct B-fragment rows
// (n=lane&15, k=quad*8+j) for k_fused's MFMA, read straight from L2.

__global__ void k_wsT(const float* __restrict__ W1, const float* __restrict__ W2,
                      ushort_t* __restrict__ WsT) {
  int idx = blockIdx.x * 256 + threadIdx.x;   // ((l*8+r)*128 + k)*128 + n
  int n = idx & 127;
  int k = (idx >> 7) & 127;
  int rl = idx >> 14;                          // l*8 + r
  const float* W = (rl >> 3) ? W2 : W1;
  int r = rl & 7;
  float v = W[((size_t)r * 128 + k) * 128 + n];
  WsT[((size_t)rl * 128 + n) * 128 + k] = fToBf(v);
}

// wqk[layer][16][128] bf16: rows 0..7 = Wq[r] = W_r @ q, rows 8..15 = Wk[r].
__global__ void k_wqwk(const float* __restrict__ W1, const float* __restrict__ q1,
                       const float* __restrict__ k1, const float* __restrict__ W2,
                       const float* __restrict__ q2, const float* __restrict__ k2,
                       ushort_t* __restrict__ wqk) {
  int g = blockIdx.x * 256 + threadIdx.x;   // 0..4095
  if (g >= 4096) return;
  int layer = g >> 11;
  int which = (g >> 10) & 1;
  int idx = g & 1023;                        // r*128 + kin
  const float* w = (layer ? W2 : W1) + (size_t)idx * 128;
  const float* v = layer ? (which ? k2 : q2) : (which ? k1 : q1);
  float s = 0.f;
  #pragma unroll 8
  for (int h = 0; h < 128; h++) s += w[h] * v[h];
  int r = idx >> 7, kin = idx & 127;
  wqk[(size_t)layer * 2048 + ((which << 3) + r) * 128 + kin] = fToBf(s);
}

// ------------------------------- score pass --------------------------------
// stbl[node][16] = x[node] @ Wqk^T (MFMA, conventions R1/R2-verified).
// F32IN additionally emits xb (bf16 cast of x) for k_fused.

template <bool F32IN>
__global__ __launch_bounds__(256) void
k_score(const void* __restrict__ Ain,       // [M][128] f32 or bf16 node feats
        const ushort_t* __restrict__ Wqk,   // [16][128] this layer
        ushort_t* __restrict__ xb,          // [M][128] bf16 out (F32IN only)
        float* __restrict__ stbl,           // [M][16] out
        int M) {
  int tid = threadIdx.x, wv = tid >> 6, lane = tid & 63;
  int l15 = lane & 15, quad = lane >> 4;
  int node0 = blockIdx.x * 128 + wv * 32;

  bf16x8 bx[2][4];
  #pragma unroll
  for (int tile = 0; tile < 2; tile++) {
    int node = node0 + tile * 16 + l15;
    int nc = node < M ? node : M - 1;
    if (F32IN) {
      const float* row = (const float*)Ain + (size_t)nc * 128;
      #pragma unroll
      for (int kb = 0; kb < 4; kb++) {
        float4 a = *(const float4*)(row + kb * 32 + quad * 8);
        float4 b = *(const float4*)(row + kb * 32 + quad * 8 + 4);
        union { bf16x8 v; ushort_t u[8]; } t;
        t.u[0] = fToBf(a.x); t.u[1] = fToBf(a.y); t.u[2] = fToBf(a.z); t.u[3] = fToBf(a.w);
        t.u[4] = fToBf(b.x); t.u[5] = fToBf(b.y); t.u[6] = fToBf(b.z); t.u[7] = fToBf(b.w);
        bx[tile][kb] = t.v;
      }
    } else {
      const ushort_t* row = (const ushort_t*)Ain + (size_t)nc * 128;
      #pragma unroll
      for (int kb = 0; kb < 4; kb++)
        bx[tile][kb] = *(const bf16x8*)(row + kb * 32 + quad * 8);
    }
  }

  if (F32IN) {
    #pragma unroll
    for (int tile = 0; tile < 2; tile++) {
      int node = node0 + tile * 16 + l15;
      if (node < M) {
        #pragma unroll
        for (int kb = 0; kb < 4; kb++)
          *(bf16x8*)(xb + (size_t)node * 128 + kb * 32 + quad * 8) = bx[tile][kb];
      }
    }
  }

  bf16x8 aq[4];
  #pragma unroll
  for (int kb = 0; kb < 4; kb++)
    aq[kb] = *(const bf16x8*)(Wqk + (size_t)l15 * 128 + kb * 32 + quad * 8);
  #pragma unroll
  for (int tile = 0; tile < 2; tile++) {
    f32x4 s = {};
    #pragma unroll
    for (int kb = 0; kb < 4; kb++)
      s = __builtin_amdgcn_mfma_f32_16x16x32_bf16(aq[kb], bx[tile][kb], s, 0, 0, 0);
    int node = node0 + tile * 16 + l15;
    if (node < M) {
      float4 v = {s[0], s[1], s[2], s[3]};
      *(float4*)(stbl + (size_t)node * 16 + quad * 4) = v;
    }
  }
}

// ------------------------ per-edge softmax weights -------------------------
// One wave per target: m, den over [rp2[t*8], rp2[t*8+8]); writes per edge
// ew[e] = {src, bits(exp(alpha-m)/(den+1e-16))}. Fast path deg<=64 keeps
// alpha in registers; rare long path recomputes.

__global__ __launch_bounds__(256) void
k_weights(const float* __restrict__ stbl, const int* __restrict__ rp2,
          const int* __restrict__ sorted, int2* __restrict__ ew, int n) {
  int tid = threadIdx.x, wv = tid >> 6, lane = tid & 63;
  int t = blockIdx.x * 4 + wv;
  if (t >= n) return;
  int e0 = rp2[t * 8], e1 = rp2[t * 8 + 8];
  int deg = e1 - e0;
  if (deg <= 0) return;

  if (deg <= 64) {
    float alpha = -INFINITY;
    int pk = 0;
    if (lane < deg) {
      pk = sorted[e0 + lane];
      int s = pk & 0xFFFF, r = pk >> 16;
      float a = stbl[(size_t)t * 16 + r] + stbl[(size_t)s * 16 + 8 + r];
      alpha = (a >= 0.f) ? a : 0.2f * a;   // leaky_relu 0.2
    }
    float m = alpha;
    #pragma unroll
    for (int off = 32; off; off >>= 1) m = fmaxf(m, __shfl_xor(m, off, 64));
    float w = (lane < deg) ? __expf(alpha - m) : 0.f;
    float den = w;
    #pragma unroll
    for (int off = 32; off; off >>= 1) den += __shfl_xor(den, off, 64);
    float inv = 1.f / (den + 1e-16f);
    if (lane < deg) {
      int2 o;
      o.x = pk & 0xFFFF;
      o.y = __float_as_int(w * inv);
      ew[e0 + lane] = o;
    }
  } else {
    float m = -INFINITY, den = 0.f;
    for (int base = e0; base < e1; base += 64) {
      int cnt = min(64, e1 - base);
      float alpha = -INFINITY;
      if (lane < cnt) {
        int pk = sorted[base + lane];
        int s = pk & 0xFFFF, r = pk >> 16;
        float a = stbl[(size_t)t * 16 + r] + stbl[(size_t)s * 16 + 8 + r];
        alpha = (a >= 0.f) ? a : 0.2f * a;
      }
      float cm = alpha;
      #pragma unroll
      for (int off = 32; off; off >>= 1) cm = fmaxf(cm, __shfl_xor(cm, off, 64));
      float nm = fmaxf(m, cm);
      float w = (lane < cnt) ? __expf(alpha - nm) : 0.f;
      float ws = w;
      #pragma unroll
      for (int off = 32; off; off >>= 1) ws += __shfl_xor(ws, off, 64);
      den = den * __expf(m - nm) + ws;
      m = nm;
    }
    float inv = 1.f / (den + 1e-16f);
    for (int base = e0; base < e1; base += 64) {
      int cnt = min(64, e1 - base);
      if (lane < cnt) {
        int pk = sorted[base + lane];
        int s = pk & 0xFFFF, r = pk >> 16;
        float a = stbl[(size_t)t * 16 + r] + stbl[(size_t)s * 16 + 8 + r];
        a = (a >= 0.f) ? a : 0.2f * a;
        int2 o;
        o.x = pk & 0xFFFF;
        o.y = __float_as_int(__expf(a - m) * inv);
        ew[base + lane] = o;
      }
    }
  }
}

// ----------------- fused pooled-gather + output GEMM -----------------------
// h[t] = relu( sum_r ( sum_{e in (t,r)} w_e x[src_e] ) @ W_r + b ).
// Block = 256 thr = 4 independent waves; wave owns 16 targets (one MFMA
// M-tile). Per relation r: pool the 16 (t,r) runs (2 ch/lane f32, 2-wide
// edge unroll for load ILP), pack bf16 rows into own LDS As slice, then
// 8ct x 4kb MFMA with B-frags loaded directly from WsT[r] (L2-hot).
// acc[8] f32x4 persists across r. NO __syncthreads anywhere.
// Fragment conventions as k_gemmL (verified): A-frag m=lane&15, k=quad*8+j;
// B-frag n=lane&15, k=quad*8+j; C/D row=quad*4+reg, col=lane&15.

#define LDA 136

__global__ __launch_bounds__(256, 4) void
k_fused(const ushort_t* __restrict__ feat,   // [M][128] bf16 node feats
        const int* __restrict__ rp2,         // [M*8+1]
        const int2* __restrict__ ew,         // [E] {src, w bits}
        const ushort_t* __restrict__ WsT,    // [8][128][128] this layer
        const float* __restrict__ bias,
        ushort_t* __restrict__ h,            // [M][128] bf16 out
        int M) {
  __shared__ __align__(16) ushort_t As[64 * LDA];
  int tid = threadIdx.x, wv = tid >> 6, lane = tid & 63;
  int l15 = lane & 15, quad = lane >> 4;
  int t0 = blockIdx.x * 64 + wv * 16;
  const uint* fx = (const uint*)feat;
  uint* asu = (uint*)As;                     // row stride LDA/2 = 68 uints
  f32x4 acc[8] = {};

  for (int r = 0; r < 8; r++) {
    // ---- pool 16 targets' (t,r) runs into own As rows ----
    for (int i = 0; i < 16; i++) {
      int t = t0 + i;
      float ga = 0.f, gb = 0.f;
      if (t < M) {
        int e = rp2[t * 8 + r], eend = rp2[t * 8 + r + 1];
        for (; e + 1 < eend; e += 2) {       // 2 independent row loads in flight
          int2 p0 = ew[e];
          int2 p1 = ew[e + 1];
          uint v0 = fx[(size_t)p0.x * 64 + lane];
          uint v1 = fx[(size_t)p1.x * 64 + lane];
          float w0 = __int_as_float(p0.y);
          float w1 = __int_as_float(p1.y);
          ga = __builtin_fmaf(w0, bfToF((ushort_t)(v0 & 0xFFFF)), ga);
          gb = __builtin_fmaf(w0, bfToF((ushort_t)(v0 >> 16)), gb);
          ga = __builtin_fmaf(w1, bfToF((ushort_t)(v1 & 0xFFFF)), ga);
          gb = __builtin_fmaf(w1, bfToF((ushort_t)(v1 >> 16)), gb);
        }
        if (e < eend) {
          int2 p = ew[e];
          uint v = fx[(size_t)p.x * 64 + lane];
          float w = __int_as_float(p.y);
          ga = __builtin_fmaf(w, bfToF((ushort_t)(v & 0xFFFF)), ga);
          gb = __builtin_fmaf(w, bfToF((ushort_t)(v >> 16)), gb);
        }
      }
      asu[(wv * 16 + i) * (LDA / 2) + lane] = packBf(ga, gb);
    }
    // ---- MFMA: own 16 rows x 128 cols, K=128 ----
    bf16x8 afr[4];
    #pragma unroll
    for (int kb = 0; kb < 4; kb++)
      afr[kb] = *(const bf16x8*)(As + (size_t)(wv * 16 + l15) * LDA + kb * 32 + quad * 8);
    const ushort_t* Wr = WsT + (size_t)r * 16384;
    #pragma unroll
    for (int ct = 0; ct < 8; ct++)
      #pragma unroll
      for (int kb = 0; kb < 4; kb++) {
        bf16x8 bfr = *(const bf16x8*)(Wr + (size_t)(ct * 16 + l15) * 128 + kb * 32 + quad * 8);
        acc[ct] = __builtin_amdgcn_mfma_f32_16x16x32_bf16(afr[kb], bfr, acc[ct], 0, 0, 0);
      }
  }

  // ---- epilogue: bias + relu -> bf16 ----
  #pragma unroll
  for (int ct = 0; ct < 8; ct++) {
    float b = bias[ct * 16 + l15];
    #pragma unroll
    for (int reg = 0; reg < 4; reg++) {
      int rr = t0 + quad * 4 + reg;
      if (rr < M)
        h[(size_t)rr * 128 + ct * 16 + l15] = fToBf(fmaxf(acc[ct][reg] + b, 0.f));
    }
  }
}

// ----------------------------- final linear --------------------------------

__global__ __launch_bounds__(256) void
k_gemmL(const ushort_t* __restrict__ A, const float* __restrict__ Wl,
        float* __restrict__ Cout, const float* __restrict__ bias, int M) {
  __shared__ ushort_t As[64 * LDA];
  __shared__ ushort_t Bs[128 * LDA];
  int tid = threadIdx.x;
  int row0 = blockIdx.x * 64;
  for (int c = tid; c < 1024; c += 256) {
    int r = c >> 4, off = (c & 15) * 8;
    int4 v = {0, 0, 0, 0};
    if (row0 + r < M) v = *(const int4*)(A + (size_t)(row0 + r) * 128 + off);
    *(int4*)(As + r * LDA + off) = v;
  }
  for (int c = tid; c < 2048; c += 256) {
    int nn = c >> 4, off = (c & 15) * 8;
    float4 a = *(const float4*)(Wl + (size_t)nn * 128 + off);
    float4 b = *(const float4*)(Wl + (size_t)nn * 128 + off + 4);
    ushort_t* d = Bs + nn * LDA + off;
    d[0] = fToBf(a.x); d[1] = fToBf(a.y); d[2] = fToBf(a.z); d[3] = fToBf(a.w);
    d[4] = fToBf(b.x); d[5] = fToBf(b.y); d[6] = fToBf(b.z); d[7] = fToBf(b.w);
  }
  __syncthreads();
  int wv = tid >> 6, lane = tid & 63;
  int l15 = lane & 15, quad = lane >> 4;
  int wr = wv * 16;
  bf16x8 afr[4];
  #pragma unroll
  for (int kb = 0; kb < 4; kb++)
    afr[kb] = *reinterpret_cast<const bf16x8*>(As + (wr + l15) * LDA + kb * 32 + quad * 8);
  f32x4 acc[8] = {};
  #pragma unroll
  for (int ct = 0; ct < 8; ct++)
    #pragma unroll
    for (int kb = 0; kb < 4; kb++) {
      bf16x8 bfr = *reinterpret_cast<const bf16x8*>(Bs + (ct * 16 + l15) * LDA + kb * 32 + quad * 8);
      acc[ct] = __builtin_amdgcn_mfma_f32_16x16x32_bf16(afr[kb], bfr, acc[ct], 0, 0, 0);
    }
  #pragma unroll
  for (int ct = 0; ct < 8; ct++)
    #pragma unroll
    for (int reg = 0; reg < 4; reg++) {
      int rr = row0 + wr + quad * 4 + reg;
      if (rr < M) Cout[(size_t)rr * 128 + ct * 16 + l15] = acc[ct][reg] + bias[ct * 16 + l15];
    }
}

// ------------------------------- launcher ----------------------------------

extern "C" void kernel_launch(void* const* d_in, const int* in_sizes, int n_in,
                              void* d_out, int out_size, void* d_ws, size_t ws_size,
                              hipStream_t stream) {
  const float* x   = (const float*)d_in[0];
  const int* ei    = (const int*)d_in[1];
  const int* etype = (const int*)d_in[2];
  const float* W1  = (const float*)d_in[4];
  const float* q1  = (const float*)d_in[5];
  const float* k1  = (const float*)d_in[6];
  const float* b1  = (const float*)d_in[7];
  const float* W2  = (const float*)d_in[8];
  const float* q2  = (const float*)d_in[9];
  const float* k2  = (const float*)d_in[10];
  const float* b2  = (const float*)d_in[11];
  const float* Wl  = (const float*)d_in[12];
  const float* bl  = (const float*)d_in[13];
  float* out       = (float*)d_out;

  const int N = in_sizes[0] / 128;   // 50000
  const int E = in_sizes[2];         // 800000

  char* ws = (char*)d_ws;
  size_t off = 0;
  auto alloc = [&](size_t bytes) {
    size_t o = off;
    off = (off + bytes + 255) & ~(size_t)255;
    return o;
  };

  ushort_t* h1    = (ushort_t*)(ws + alloc((size_t)N * 128 * 2));
  ushort_t* xbh2  = (ushort_t*)(ws + alloc((size_t)N * 128 * 2));    // xb then h2
  ushort_t* WsT   = (ushort_t*)(ws + alloc((size_t)2 * 8 * 16384 * 2));
  ushort_t* wqk   = (ushort_t*)(ws + alloc(2 * 16 * 128 * 2));
  float* stbl     = (float*)(ws + alloc((size_t)N * 16 * 4));
  int2* ew        = (int2*)(ws + alloc((size_t)E * 8));
  int* deg2       = (int*)(ws + alloc((size_t)N * 8 * 4));
  int* cursor2    = (int*)(ws + alloc((size_t)N * 8 * 4));
  int* incl2      = (int*)(ws + alloc((size_t)N * 8 * 4));
  int* rowptr2    = (int*)(ws + alloc((size_t)(N * 8 + 1) * 4));
  int* bsum       = (int*)(ws + alloc(2048 * 4));
  int* sorted     = (int*)(ws + alloc((size_t)E * 4));
  (void)ws_size; (void)n_in; (void)out_size;

  const int* srcp = ei;
  const int* tgtp = ei + E;

  int n2 = N * 8;                    // 400000 segments
  int gE  = (E + 255) / 256;
  int gN2 = (n2 + 255) / 256;        // 1563
  int gS  = (N + 127) / 128;         // k_score: 391
  int gW  = (N + 3) / 4;             // k_weights: 12500
  int gF  = (N + 63) / 64;           // k_fused / k_gemmL: 782

  // CSR build on (target, relation) segments (once; same graph both layers)
  hipMemsetAsync(deg2, 0, (size_t)n2 * 4, stream);
  hipMemsetAsync(cursor2, 0, (size_t)n2 * 4, stream);
  k_count2<<<gE, 256, 0, stream>>>(tgtp, etype, deg2, E);
  k_scanA<<<gN2, 256, 0, stream>>>(deg2, incl2, bsum, n2);
  k_scanB2<<<1, 256, 0, stream>>>(bsum, gN2);
  k_scanC<<<gN2, 256, 0, stream>>>(deg2, incl2, bsum, rowptr2, n2, E);
  k_scatter2<<<gE, 256, 0, stream>>>(srcp, tgtp, etype, rowptr2, cursor2, sorted, E);

  // weight prep (both layers)
  k_wsT<<<1024, 256, 0, stream>>>(W1, W2, WsT);
  k_wqwk<<<16, 256, 0, stream>>>(W1, q1, k1, W2, q2, k2, wqk);

  // layer 1
  k_score<true><<<gS, 256, 0, stream>>>(x, wqk, xbh2, stbl, N);
  k_weights<<<gW, 256, 0, stream>>>(stbl, rowptr2, sorted, ew, N);
  k_fused<<<gF, 256, 0, stream>>>(xbh2, rowptr2, ew, WsT, b1, h1, N);

  // layer 2 (xb buffer is dead after fused1; reused as h2 below)
  k_score<false><<<gS, 256, 0, stream>>>(h1, wqk + 2048, nullptr, stbl, N);
  k_weights<<<gW, 256, 0, stream>>>(stbl, rowptr2, sorted, ew, N);
  k_fused<<<gF, 256, 0, stream>>>(h1, rowptr2, ew, WsT + (size_t)8 * 16384, b2, xbh2, N);

  // final linear
  k_gemmL<<<gF, 256, 0, stream>>>(xbh2, Wl, out, bl, N);
}

// Round 5
// 565.546 us; speedup vs baseline: 1.2634x; 1.2634x over previous
//
#include <hip/hip_runtime.h>

// ---------------------------------------------------------------------------
// RGAT encoder: N=50000, E=800000, R=8, IN=H=128, B=10.
// R13: fused pooling+GEMM with R11-grade pooling parallelism.
//      R12 failed (233us): 16 serial targets/wave, 128 tiny runs, <=2 loads in
//      flight. R13: block = 512 thr = 8 waves / 16 targets -> 2 targets/wave
//      (25000 pooling waves, like R11's 50000), 4-wide edge unroll (4 gather
//      rows in flight), softmax fused (k_weights deleted), pooled rows written
//      to padded LDS As[16][1032]; ONE barrier; each wave MFMAs one ct tile
//      (K=1024) with B-frags from L2-hot WsT. No g / ew round-trips.
//      Per layer: k_score -> k_fused2. CSR on (t,r) segments as R11/R12.
// ---------------------------------------------------------------------------

typedef unsigned int uint;
typedef unsigned short ushort_t;

using bf16x8 = __attribute__((ext_vector_type(8))) __bf16;
using f32x4  = __attribute__((ext_vector_type(4))) float;

__device__ __forceinline__ ushort_t fToBf(float f) {
  uint u = __float_as_uint(f);
  u += 0x7FFFu + ((u >> 16) & 1);   // round-to-nearest-even
  return (ushort_t)(u >> 16);
}
__device__ __forceinline__ float bfToF(ushort_t h) {
  return __uint_as_float(((uint)h) << 16);
}
__device__ __forceinline__ uint packBf(float a, float b) {
  return (uint)fToBf(a) | ((uint)fToBf(b) << 16);
}

// ------------------------------- CSR build ---------------------------------
// Segments keyed on t8r = tgt*8 + rel (400k segments).

__global__ void k_count2(const int* __restrict__ tgt, const int* __restrict__ et,
                         int* __restrict__ deg2, int E) {
  int e = blockIdx.x * 256 + threadIdx.x;
  if (e < E) atomicAdd(&deg2[tgt[e] * 8 + et[e]], 1);
}

__global__ void k_scanA(const int* __restrict__ deg, int* __restrict__ incl,
                        int* __restrict__ bsum, int n) {
  __shared__ int s[256];
  int tid = threadIdx.x;
  int i = blockIdx.x * 256 + tid;
  int v = (i < n) ? deg[i] : 0;
  s[tid] = v;
  __syncthreads();
  for (int off = 1; off < 256; off <<= 1) {
    int t = (tid >= off) ? s[tid - off] : 0;
    __syncthreads();
    s[tid] += t;
    __syncthreads();
  }
  if (i < n) incl[i] = s[tid];
  if (tid == 255) bsum[blockIdx.x] = s[255];
}

// single-block chunked exclusive scan of bsum[nb]
__global__ void k_scanB2(int* __restrict__ bsum, int nb) {
  __shared__ int s[256];
  __shared__ int carry;
  int tid = threadIdx.x;
  if (tid == 0) carry = 0;
  __syncthreads();
  for (int base = 0; base < nb; base += 256) {
    int i = base + tid;
    int v = (i < nb) ? bsum[i] : 0;
    s[tid] = v;
    __syncthreads();
    for (int off = 1; off < 256; off <<= 1) {
      int t = (tid >= off) ? s[tid - off] : 0;
      __syncthreads();
      s[tid] += t;
      __syncthreads();
    }
    int c = carry;
    if (i < nb) bsum[i] = c + s[tid] - v;   // exclusive
    __syncthreads();
    if (tid == 255) carry = c + s[255];
    __syncthreads();
  }
}

__global__ void k_scanC(const int* __restrict__ deg, const int* __restrict__ incl,
                        const int* __restrict__ bsum, int* __restrict__ rowptr,
                        int n, int E) {
  int i = blockIdx.x * 256 + threadIdx.x;
  if (i < n) {
    rowptr[i] = bsum[blockIdx.x] + incl[i] - deg[i];
    if (i == n - 1) rowptr[n] = E;
  }
}

__global__ void k_scatter2(const int* __restrict__ src, const int* __restrict__ tgt,
                           const int* __restrict__ et, const int* __restrict__ rowptr2,
                           int* __restrict__ cursor2, int* __restrict__ sorted, int E) {
  int e = blockIdx.x * 256 + threadIdx.x;
  if (e >= E) return;
  int t8r = tgt[e] * 8 + et[e];
  int pos = atomicAdd(&cursor2[t8r], 1);
  sorted[rowptr2[t8r] + pos] = src[e] | (et[e] << 16);   // src < 65536, rel < 8
}

// ------------------------------ weight prep --------------------------------
// WsT[layer][r][n=128][k=128] bf16, value = W[r][k][n]: direct B-fragment rows.

__global__ void k_wsT(const float* __restrict__ W1, const float* __restrict__ W2,
                      ushort_t* __restrict__ WsT) {
  int idx = blockIdx.x * 256 + threadIdx.x;   // ((l*8+r)*128 + k)*128 + n
  int n = idx & 127;
  int k = (idx >> 7) & 127;
  int rl = idx >> 14;                          // l*8 + r
  const float* W = (rl >> 3) ? W2 : W1;
  int r = rl & 7;
  float v = W[((size_t)r * 128 + k) * 128 + n];
  WsT[((size_t)rl * 128 + n) * 128 + k] = fToBf(v);
}

// wqk[layer][16][128] bf16: rows 0..7 = Wq[r] = W_r @ q, rows 8..15 = Wk[r].
__global__ void k_wqwk(const float* __restrict__ W1, const float* __restrict__ q1,
                       const float* __restrict__ k1, const float* __restrict__ W2,
                       const float* __restrict__ q2, const float* __restrict__ k2,
                       ushort_t* __restrict__ wqk) {
  int g = blockIdx.x * 256 + threadIdx.x;   // 0..4095
  if (g >= 4096) return;
  int layer = g >> 11;
  int which = (g >> 10) & 1;
  int idx = g & 1023;                        // r*128 + kin
  const float* w = (layer ? W2 : W1) + (size_t)idx * 128;
  const float* v = layer ? (which ? k2 : q2) : (which ? k1 : q1);
  float s = 0.f;
  #pragma unroll 8
  for (int h = 0; h < 128; h++) s += w[h] * v[h];
  int r = idx >> 7, kin = idx & 127;
  wqk[(size_t)layer * 2048 + ((which << 3) + r) * 128 + kin] = fToBf(s);
}

// ------------------------------- score pass --------------------------------
// stbl[node][16] = x[node] @ Wqk^T. F32IN additionally emits xb (bf16 cast).

template <bool F32IN>
__global__ __launch_bounds__(256) void
k_score(const void* __restrict__ Ain,       // [M][128] f32 or bf16 node feats
        const ushort_t* __restrict__ Wqk,   // [16][128] this layer
        ushort_t* __restrict__ xb,          // [M][128] bf16 out (F32IN only)
        float* __restrict__ stbl,           // [M][16] out
        int M) {
  int tid = threadIdx.x, wv = tid >> 6, lane = tid & 63;
  int l15 = lane & 15, quad = lane >> 4;
  int node0 = blockIdx.x * 128 + wv * 32;

  bf16x8 bx[2][4];
  #pragma unroll
  for (int tile = 0; tile < 2; tile++) {
    int node = node0 + tile * 16 + l15;
    int nc = node < M ? node : M - 1;
    if (F32IN) {
      const float* row = (const float*)Ain + (size_t)nc * 128;
      #pragma unroll
      for (int kb = 0; kb < 4; kb++) {
        float4 a = *(const float4*)(row + kb * 32 + quad * 8);
        float4 b = *(const float4*)(row + kb * 32 + quad * 8 + 4);
        union { bf16x8 v; ushort_t u[8]; } t;
        t.u[0] = fToBf(a.x); t.u[1] = fToBf(a.y); t.u[2] = fToBf(a.z); t.u[3] = fToBf(a.w);
        t.u[4] = fToBf(b.x); t.u[5] = fToBf(b.y); t.u[6] = fToBf(b.z); t.u[7] = fToBf(b.w);
        bx[tile][kb] = t.v;
      }
    } else {
      const ushort_t* row = (const ushort_t*)Ain + (size_t)nc * 128;
      #pragma unroll
      for (int kb = 0; kb < 4; kb++)
        bx[tile][kb] = *(const bf16x8*)(row + kb * 32 + quad * 8);
    }
  }

  if (F32IN) {
    #pragma unroll
    for (int tile = 0; tile < 2; tile++) {
      int node = node0 + tile * 16 + l15;
      if (node < M) {
        #pragma unroll
        for (int kb = 0; kb < 4; kb++)
          *(bf16x8*)(xb + (size_t)node * 128 + kb * 32 + quad * 8) = bx[tile][kb];
      }
    }
  }

  bf16x8 aq[4];
  #pragma unroll
  for (int kb = 0; kb < 4; kb++)
    aq[kb] = *(const bf16x8*)(Wqk + (size_t)l15 * 128 + kb * 32 + quad * 8);
  #pragma unroll
  for (int tile = 0; tile < 2; tile++) {
    f32x4 s = {};
    #pragma unroll
    for (int kb = 0; kb < 4; kb++)
      s = __builtin_amdgcn_mfma_f32_16x16x32_bf16(aq[kb], bx[tile][kb], s, 0, 0, 0);
    int node = node0 + tile * 16 + l15;
    if (node < M) {
      float4 v = {s[0], s[1], s[2], s[3]};
      *(float4*)(stbl + (size_t)node * 16 + quad * 4) = v;
    }
  }
}

// ------------- fused softmax + pooled gather + output GEMM -----------------
// h[t] = relu( sum_r ( sum_{e in (t,r)} w_e x[src_e] ) @ W_r + b ).
// Block = 512 thr = 8 waves, 16 targets (2/wave -> R11-grade parallelism).
// Per target: phase A softmax weights into LDS (deg<=64 fast path; rare long
// path recomputes per edge); phase B per-relation pooling, 4-wide edge unroll
// (4 x 256 B gather rows in flight), flush bf16 rows to As[16][LDK].
// ONE barrier, then each wave computes one 16x16 ct tile over K=1024 with
// B-frags streamed from L2-hot WsT. Epilogue bias+relu -> h (standard order).
// Fragment conventions (verified): A-frag m=lane&15, k=quad*8+j; B-frag
// n=lane&15, k=quad*8+j; C/D row=quad*4+reg, col=lane&15.

#define LDK 1032   // As row stride in bf16 (odd 16B-slot stride -> spread banks)

__global__ __launch_bounds__(512, 4) void
k_fused2(const ushort_t* __restrict__ feat,  // [M][128] bf16 node feats
         const float* __restrict__ stbl,     // [M][16]: 0..7 q-side, 8..15 k-side
         const int* __restrict__ rp2,        // [M*8+1]
         const int* __restrict__ sorted,     // src | (rel<<16), rel-sorted per t
         const ushort_t* __restrict__ WsT,   // [8][128][128] this layer
         const float* __restrict__ bias,
         ushort_t* __restrict__ h,           // [M][128] bf16 out
         int M) {
  __shared__ __align__(16) ushort_t As[16 * LDK];   // 33 KB
  __shared__ int   s_pk[8][64];
  __shared__ float s_w[8][64];
  int tid = threadIdx.x, wv = tid >> 6, lane = tid & 63;
  int l15 = lane & 15, quad = lane >> 4;
  int t0 = blockIdx.x * 16;
  const uint* fx = (const uint*)feat;
  uint* asu = (uint*)As;                            // row stride LDK/2 = 516

  for (int sub = 0; sub < 2; sub++) {
    int tl = wv * 2 + sub;                          // local target 0..15
    int t = t0 + tl;
    uint* arow = asu + (size_t)tl * (LDK / 2);
    if (t < M) {
      int e0 = rp2[t * 8], e1 = rp2[t * 8 + 8];
      int deg = e1 - e0;
      float m = -INFINITY, inv = 0.f;
      bool fast = (deg <= 64);

      // ---- phase A: softmax weights ----
      if (fast) {
        float alpha = -INFINITY;
        int pk = 0;
        if (lane < deg) {
          pk = sorted[e0 + lane];
          int s = pk & 0xFFFF, r = pk >> 16;
          float a = stbl[(size_t)t * 16 + r] + stbl[(size_t)s * 16 + 8 + r];
          alpha = (a >= 0.f) ? a : 0.2f * a;        // leaky_relu 0.2
        }
        m = alpha;
        #pragma unroll
        for (int off = 32; off; off >>= 1) m = fmaxf(m, __shfl_xor(m, off, 64));
        float w = (lane < deg) ? __expf(alpha - m) : 0.f;
        float den = w;
        #pragma unroll
        for (int off = 32; off; off >>= 1) den += __shfl_xor(den, off, 64);
        inv = 1.f / (den + 1e-16f);
        s_pk[wv][lane] = pk;
        s_w[wv][lane] = w * inv;
      } else {
        float den = 0.f;
        for (int base = e0; base < e1; base += 64) {
          int cnt = min(64, e1 - base);
          float alpha = -INFINITY;
          if (lane < cnt) {
            int pk = sorted[base + lane];
            int s = pk & 0xFFFF, r = pk >> 16;
            float a = stbl[(size_t)t * 16 + r] + stbl[(size_t)s * 16 + 8 + r];
            alpha = (a >= 0.f) ? a : 0.2f * a;
          }
          float cm = alpha;
          #pragma unroll
          for (int off = 32; off; off >>= 1) cm = fmaxf(cm, __shfl_xor(cm, off, 64));
          float nm = fmaxf(m, cm);
          float w = (lane < cnt) ? __expf(alpha - nm) : 0.f;
          float ws = w;
          #pragma unroll
          for (int off = 32; off; off >>= 1) ws += __shfl_xor(ws, off, 64);
          den = den * __expf(m - nm) + ws;
          m = nm;
        }
        inv = 1.f / (den + 1e-16f);
      }

      // ---- phase B: per-relation pooling (4 gather rows in flight) ----
      #pragma unroll 1
      for (int r = 0; r < 8; r++) {
        int rs = rp2[t * 8 + r], re = rp2[t * 8 + r + 1];
        float ga = 0.f, gb = 0.f;
        if (fast) {
          int i = rs - e0, iend = re - e0;
          for (; i + 3 < iend; i += 4) {
            int p0 = s_pk[wv][i],     p1 = s_pk[wv][i + 1];
            int p2 = s_pk[wv][i + 2], p3 = s_pk[wv][i + 3];
            float w0 = s_w[wv][i],     w1 = s_w[wv][i + 1];
            float w2 = s_w[wv][i + 2], w3 = s_w[wv][i + 3];
            uint v0 = fx[(size_t)(p0 & 0xFFFF) * 64 + lane];
            uint v1 = fx[(size_t)(p1 & 0xFFFF) * 64 + lane];
            uint v2 = fx[(size_t)(p2 & 0xFFFF) * 64 + lane];
            uint v3 = fx[(size_t)(p3 & 0xFFFF) * 64 + lane];
            ga = __builtin_fmaf(w0, bfToF((ushort_t)(v0 & 0xFFFF)), ga);
            gb = __builtin_fmaf(w0, bfToF((ushort_t)(v0 >> 16)), gb);
            ga = __builtin_fmaf(w1, bfToF((ushort_t)(v1 & 0xFFFF)), ga);
            gb = __builtin_fmaf(w1, bfToF((ushort_t)(v1 >> 16)), gb);
            ga = __builtin_fmaf(w2, bfToF((ushort_t)(v2 & 0xFFFF)), ga);
            gb = __builtin_fmaf(w2, bfToF((ushort_t)(v2 >> 16)), gb);
            ga = __builtin_fmaf(w3, bfToF((ushort_t)(v3 & 0xFFFF)), ga);
            gb = __builtin_fmaf(w3, bfToF((ushort_t)(v3 >> 16)), gb);
          }
          for (; i < iend; i++) {
            int p = s_pk[wv][i];
            float w = s_w[wv][i];
            uint v = fx[(size_t)(p & 0xFFFF) * 64 + lane];
            ga = __builtin_fmaf(w, bfToF((ushort_t)(v & 0xFFFF)), ga);
            gb = __builtin_fmaf(w, bfToF((ushort_t)(v >> 16)), gb);
          }
        } else {
          for (int e = rs; e < re; e++) {
            int pk = sorted[e];                      // uniform -> broadcast
            int s = pk & 0xFFFF;
            float a = stbl[(size_t)t * 16 + r] + stbl[(size_t)s * 16 + 8 + r];
            a = (a >= 0.f) ? a : 0.2f * a;
            float w = __expf(a - m) * inv;
            uint v = fx[(size_t)s * 64 + lane];
            ga = __builtin_fmaf(w, bfToF((ushort_t)(v & 0xFFFF)), ga);
            gb = __builtin_fmaf(w, bfToF((ushort_t)(v >> 16)), gb);
          }
        }
        arow[r * 64 + lane] = packBf(ga, gb);
      }
    } else {
      #pragma unroll
      for (int r = 0; r < 8; r++) arow[r * 64 + lane] = 0u;
    }
  }
  __syncthreads();

  // ---- GEMM: wave wv computes ct = wv (16 targets x 16 cols), K = 1024 ----
  f32x4 acc = {};
  #pragma unroll
  for (int r = 0; r < 8; r++) {
    const ushort_t* Wr = WsT + (size_t)r * 16384 + (size_t)(wv * 16 + l15) * 128;
    #pragma unroll
    for (int kb = 0; kb < 4; kb++) {
      bf16x8 afr = *(const bf16x8*)(As + (size_t)l15 * LDK + r * 128 + kb * 32 + quad * 8);
      bf16x8 bfr = *(const bf16x8*)(Wr + kb * 32 + quad * 8);
      acc = __builtin_amdgcn_mfma_f32_16x16x32_bf16(afr, bfr, acc, 0, 0, 0);
    }
  }

  // ---- epilogue: bias + relu -> bf16 ----
  float b = bias[wv * 16 + l15];
  #pragma unroll
  for (int reg = 0; reg < 4; reg++) {
    int rr = t0 + quad * 4 + reg;
    if (rr < M)
      h[(size_t)rr * 128 + wv * 16 + l15] = fToBf(fmaxf(acc[reg] + b, 0.f));
  }
}

// ----------------------------- final linear --------------------------------

#define LDA 136

__global__ __launch_bounds__(256) void
k_gemmL(const ushort_t* __restrict__ A, const float* __restrict__ Wl,
        float* __restrict__ Cout, const float* __restrict__ bias, int M) {
  __shared__ ushort_t As[64 * LDA];
  __shared__ ushort_t Bs[128 * LDA];
  int tid = threadIdx.x;
  int row0 = blockIdx.x * 64;
  for (int c = tid; c < 1024; c += 256) {
    int r = c >> 4, off = (c & 15) * 8;
    int4 v = {0, 0, 0, 0};
    if (row0 + r < M) v = *(const int4*)(A + (size_t)(row0 + r) * 128 + off);
    *(int4*)(As + r * LDA + off) = v;
  }
  for (int c = tid; c < 2048; c += 256) {
    int nn = c >> 4, off = (c & 15) * 8;
    float4 a = *(const float4*)(Wl + (size_t)nn * 128 + off);
    float4 b = *(const float4*)(Wl + (size_t)nn * 128 + off + 4);
    ushort_t* d = Bs + nn * LDA + off;
    d[0] = fToBf(a.x); d[1] = fToBf(a.y); d[2] = fToBf(a.z); d[3] = fToBf(a.w);
    d[4] = fToBf(b.x); d[5] = fToBf(b.y); d[6] = fToBf(b.z); d[7] = fToBf(b.w);
  }
  __syncthreads();
  int wv = tid >> 6, lane = tid & 63;
  int l15 = lane & 15, quad = lane >> 4;
  int wr = wv * 16;
  bf16x8 afr[4];
  #pragma unroll
  for (int kb = 0; kb < 4; kb++)
    afr[kb] = *reinterpret_cast<const bf16x8*>(As + (wr + l15) * LDA + kb * 32 + quad * 8);
  f32x4 acc[8] = {};
  #pragma unroll
  for (int ct = 0; ct < 8; ct++)
    #pragma unroll
    for (int kb = 0; kb < 4; kb++) {
      bf16x8 bfr = *reinterpret_cast<const bf16x8*>(Bs + (ct * 16 + l15) * LDA + kb * 32 + quad * 8);
      acc[ct] = __builtin_amdgcn_mfma_f32_16x16x32_bf16(afr[kb], bfr, acc[ct], 0, 0, 0);
    }
  #pragma unroll
  for (int ct = 0; ct < 8; ct++)
    #pragma unroll
    for (int reg = 0; reg < 4; reg++) {
      int rr = row0 + wr + quad * 4 + reg;
      if (rr < M) Cout[(size_t)rr * 128 + ct * 16 + l15] = acc[ct][reg] + bias[ct * 16 + l15];
    }
}

// ------------------------------- launcher ----------------------------------

extern "C" void kernel_launch(void* const* d_in, const int* in_sizes, int n_in,
                              void* d_out, int out_size, void* d_ws, size_t ws_size,
                              hipStream_t stream) {
  const float* x   = (const float*)d_in[0];
  const int* ei    = (const int*)d_in[1];
  const int* etype = (const int*)d_in[2];
  const float* W1  = (const float*)d_in[4];
  const float* q1  = (const float*)d_in[5];
  const float* k1  = (const float*)d_in[6];
  const float* b1  = (const float*)d_in[7];
  const float* W2  = (const float*)d_in[8];
  const float* q2  = (const float*)d_in[9];
  const float* k2  = (const float*)d_in[10];
  const float* b2  = (const float*)d_in[11];
  const float* Wl  = (const float*)d_in[12];
  const float* bl  = (const float*)d_in[13];
  float* out       = (float*)d_out;

  const int N = in_sizes[0] / 128;   // 50000
  const int E = in_sizes[2];         // 800000

  char* ws = (char*)d_ws;
  size_t off = 0;
  auto alloc = [&](size_t bytes) {
    size_t o = off;
    off = (off + bytes + 255) & ~(size_t)255;
    return o;
  };

  ushort_t* h1    = (ushort_t*)(ws + alloc((size_t)N * 128 * 2));
  ushort_t* xbh2  = (ushort_t*)(ws + alloc((size_t)N * 128 * 2));    // xb then h2
  ushort_t* WsT   = (ushort_t*)(ws + alloc((size_t)2 * 8 * 16384 * 2));
  ushort_t* wqk   = (ushort_t*)(ws + alloc(2 * 16 * 128 * 2));
  float* stbl     = (float*)(ws + alloc((size_t)N * 16 * 4));
  int* deg2       = (int*)(ws + alloc((size_t)N * 8 * 4));
  int* cursor2    = (int*)(ws + alloc((size_t)N * 8 * 4));
  int* incl2      = (int*)(ws + alloc((size_t)N * 8 * 4));
  int* rowptr2    = (int*)(ws + alloc((size_t)(N * 8 + 1) * 4));
  int* bsum       = (int*)(ws + alloc(2048 * 4));
  int* sorted     = (int*)(ws + alloc((size_t)E * 4));
  (void)ws_size; (void)n_in; (void)out_size;

  const int* srcp = ei;
  const int* tgtp = ei + E;

  int n2 = N * 8;                    // 400000 segments
  int gE  = (E + 255) / 256;
  int gN2 = (n2 + 255) / 256;        // 1563
  int gS  = (N + 127) / 128;         // k_score: 391
  int gF  = (N + 15) / 16;           // k_fused2: 3125 (512-thr blocks)
  int gL  = (N + 63) / 64;           // k_gemmL: 782

  // CSR build on (target, relation) segments (once; same graph both layers)
  hipMemsetAsync(deg2, 0, (size_t)n2 * 4, stream);
  hipMemsetAsync(cursor2, 0, (size_t)n2 * 4, stream);
  k_count2<<<gE, 256, 0, stream>>>(tgtp, etype, deg2, E);
  k_scanA<<<gN2, 256, 0, stream>>>(deg2, incl2, bsum, n2);
  k_scanB2<<<1, 256, 0, stream>>>(bsum, gN2);
  k_scanC<<<gN2, 256, 0, stream>>>(deg2, incl2, bsum, rowptr2, n2, E);
  k_scatter2<<<gE, 256, 0, stream>>>(srcp, tgtp, etype, rowptr2, cursor2, sorted, E);

  // weight prep (both layers)
  k_wsT<<<1024, 256, 0, stream>>>(W1, W2, WsT);
  k_wqwk<<<16, 256, 0, stream>>>(W1, q1, k1, W2, q2, k2, wqk);

  // layer 1
  k_score<true><<<gS, 256, 0, stream>>>(x, wqk, xbh2, stbl, N);
  k_fused2<<<gF, 512, 0, stream>>>(xbh2, stbl, rowptr2, sorted, WsT, b1, h1, N);

  // layer 2 (xb buffer is dead after fused1; reused as h2 below)
  k_score<false><<<gS, 256, 0, stream>>>(h1, wqk + 2048, nullptr, stbl, N);
  k_fused2<<<gF, 512, 0, stream>>>(h1, stbl, rowptr2, sorted,
                                   WsT + (size_t)8 * 16384, b2, xbh2, N);

  // final linear
  k_gemmL<<<gL, 256, 0, stream>>>(xbh2, Wl, out, bl, N);
}

// Round 6
// 496.327 us; speedup vs baseline: 1.4396x; 1.1395x over previous
//
#include <hip/hip_runtime.h>

// ---------------------------------------------------------------------------
// RGAT encoder: N=50000, E=800000, R=8, IN=H=128, B=10.
// R14: fused softmax+pool+GEMM with lane-split relation-parallel pooling.
//      R13 lesson: runs avg 2 edges -> 4-wide unroll dead; pooling was 1 load
//      in flight/wave. R14: wave = 8 groups x 8 lanes; group g owns relation
//      g of the current target (runs contiguous in (t,r)-CSR); lane covers 16
//      channels (2x dwordx4/edge). All 8 relations pool concurrently -> 8-16
//      independent gathers in flight/wave; flush = 2 conflict-free
//      ds_write_b128 into the MFMA A-tile (single writer per (t,r) row, no
//      atomics). Block = 512 thr / 16 targets (2/wave); LDS 37 KB -> 4
//      blocks/CU. One barrier; wave wv MFMAs ct=wv (full M=16), K=1024,
//      B-frags streamed from L2-hot WsT. Epilogue bias+relu -> h.
// ---------------------------------------------------------------------------

typedef unsigned int uint;
typedef unsigned short ushort_t;

using bf16x8 = __attribute__((ext_vector_type(8))) __bf16;
using f32x4  = __attribute__((ext_vector_type(4))) float;

__device__ __forceinline__ ushort_t fToBf(float f) {
  uint u = __float_as_uint(f);
  u += 0x7FFFu + ((u >> 16) & 1);   // round-to-nearest-even
  return (ushort_t)(u >> 16);
}
__device__ __forceinline__ float bfToF(ushort_t h) {
  return __uint_as_float(((uint)h) << 16);
}
__device__ __forceinline__ uint packBf(float a, float b) {
  return (uint)fToBf(a) | ((uint)fToBf(b) << 16);
}

// ------------------------------- CSR build ---------------------------------
// Segments keyed on t8r = tgt*8 + rel (400k segments).

__global__ void k_count2(const int* __restrict__ tgt, const int* __restrict__ et,
                         int* __restrict__ deg2, int E) {
  int e = blockIdx.x * 256 + threadIdx.x;
  if (e < E) atomicAdd(&deg2[tgt[e] * 8 + et[e]], 1);
}

__global__ void k_scanA(const int* __restrict__ deg, int* __restrict__ incl,
                        int* __restrict__ bsum, int n) {
  __shared__ int s[256];
  int tid = threadIdx.x;
  int i = blockIdx.x * 256 + tid;
  int v = (i < n) ? deg[i] : 0;
  s[tid] = v;
  __syncthreads();
  for (int off = 1; off < 256; off <<= 1) {
    int t = (tid >= off) ? s[tid - off] : 0;
    __syncthreads();
    s[tid] += t;
    __syncthreads();
  }
  if (i < n) incl[i] = s[tid];
  if (tid == 255) bsum[blockIdx.x] = s[255];
}

// single-block chunked exclusive scan of bsum[nb]
__global__ void k_scanB2(int* __restrict__ bsum, int nb) {
  __shared__ int s[256];
  __shared__ int carry;
  int tid = threadIdx.x;
  if (tid == 0) carry = 0;
  __syncthreads();
  for (int base = 0; base < nb; base += 256) {
    int i = base + tid;
    int v = (i < nb) ? bsum[i] : 0;
    s[tid] = v;
    __syncthreads();
    for (int off = 1; off < 256; off <<= 1) {
      int t = (tid >= off) ? s[tid - off] : 0;
      __syncthreads();
      s[tid] += t;
      __syncthreads();
    }
    int c = carry;
    if (i < nb) bsum[i] = c + s[tid] - v;   // exclusive
    __syncthreads();
    if (tid == 255) carry = c + s[255];
    __syncthreads();
  }
}

__global__ void k_scanC(const int* __restrict__ deg, const int* __restrict__ incl,
                        const int* __restrict__ bsum, int* __restrict__ rowptr,
                        int n, int E) {
  int i = blockIdx.x * 256 + threadIdx.x;
  if (i < n) {
    rowptr[i] = bsum[blockIdx.x] + incl[i] - deg[i];
    if (i == n - 1) rowptr[n] = E;
  }
}

__global__ void k_scatter2(const int* __restrict__ src, const int* __restrict__ tgt,
                           const int* __restrict__ et, const int* __restrict__ rowptr2,
                           int* __restrict__ cursor2, int* __restrict__ sorted, int E) {
  int e = blockIdx.x * 256 + threadIdx.x;
  if (e >= E) return;
  int t8r = tgt[e] * 8 + et[e];
  int pos = atomicAdd(&cursor2[t8r], 1);
  sorted[rowptr2[t8r] + pos] = src[e] | (et[e] << 16);   // src < 65536, rel < 8
}

// ------------------------------ weight prep --------------------------------
// WsT[layer][r][n=128][k=128] bf16, value = W[r][k][n]: direct B-fragment rows.

__global__ void k_wsT(const float* __restrict__ W1, const float* __restrict__ W2,
                      ushort_t* __restrict__ WsT) {
  int idx = blockIdx.x * 256 + threadIdx.x;   // ((l*8+r)*128 + k)*128 + n
  int n = idx & 127;
  int k = (idx >> 7) & 127;
  int rl = idx >> 14;                          // l*8 + r
  const float* W = (rl >> 3) ? W2 : W1;
  int r = rl & 7;
  float v = W[((size_t)r * 128 + k) * 128 + n];
  WsT[((size_t)rl * 128 + n) * 128 + k] = fToBf(v);
}

// wqk[layer][16][128] bf16: rows 0..7 = Wq[r] = W_r @ q, rows 8..15 = Wk[r].
__global__ void k_wqwk(const float* __restrict__ W1, const float* __restrict__ q1,
                       const float* __restrict__ k1, const float* __restrict__ W2,
                       const float* __restrict__ q2, const float* __restrict__ k2,
                       ushort_t* __restrict__ wqk) {
  int g = blockIdx.x * 256 + threadIdx.x;   // 0..4095
  if (g >= 4096) return;
  int layer = g >> 11;
  int which = (g >> 10) & 1;
  int idx = g & 1023;                        // r*128 + kin
  const float* w = (layer ? W2 : W1) + (size_t)idx * 128;
  const float* v = layer ? (which ? k2 : q2) : (which ? k1 : q1);
  float s = 0.f;
  #pragma unroll 8
  for (int h = 0; h < 128; h++) s += w[h] * v[h];
  int r = idx >> 7, kin = idx & 127;
  wqk[(size_t)layer * 2048 + ((which << 3) + r) * 128 + kin] = fToBf(s);
}

// ------------------------------- score pass --------------------------------
// stbl[node][16] = x[node] @ Wqk^T. F32IN additionally emits xb (bf16 cast).

template <bool F32IN>
__global__ __launch_bounds__(256) void
k_score(const void* __restrict__ Ain,       // [M][128] f32 or bf16 node feats
        const ushort_t* __restrict__ Wqk,   // [16][128] this layer
        ushort_t* __restrict__ xb,          // [M][128] bf16 out (F32IN only)
        float* __restrict__ stbl,           // [M][16] out
        int M) {
  int tid = threadIdx.x, wv = tid >> 6, lane = tid & 63;
  int l15 = lane & 15, quad = lane >> 4;
  int node0 = blockIdx.x * 128 + wv * 32;

  bf16x8 bx[2][4];
  #pragma unroll
  for (int tile = 0; tile < 2; tile++) {
    int node = node0 + tile * 16 + l15;
    int nc = node < M ? node : M - 1;
    if (F32IN) {
      const float* row = (const float*)Ain + (size_t)nc * 128;
      #pragma unroll
      for (int kb = 0; kb < 4; kb++) {
        float4 a = *(const float4*)(row + kb * 32 + quad * 8);
        float4 b = *(const float4*)(row + kb * 32 + quad * 8 + 4);
        union { bf16x8 v; ushort_t u[8]; } t;
        t.u[0] = fToBf(a.x); t.u[1] = fToBf(a.y); t.u[2] = fToBf(a.z); t.u[3] = fToBf(a.w);
        t.u[4] = fToBf(b.x); t.u[5] = fToBf(b.y); t.u[6] = fToBf(b.z); t.u[7] = fToBf(b.w);
        bx[tile][kb] = t.v;
      }
    } else {
      const ushort_t* row = (const ushort_t*)Ain + (size_t)nc * 128;
      #pragma unroll
      for (int kb = 0; kb < 4; kb++)
        bx[tile][kb] = *(const bf16x8*)(row + kb * 32 + quad * 8);
    }
  }

  if (F32IN) {
    #pragma unroll
    for (int tile = 0; tile < 2; tile++) {
      int node = node0 + tile * 16 + l15;
      if (node < M) {
        #pragma unroll
        for (int kb = 0; kb < 4; kb++)
          *(bf16x8*)(xb + (size_t)node * 128 + kb * 32 + quad * 8) = bx[tile][kb];
      }
    }
  }

  bf16x8 aq[4];
  #pragma unroll
  for (int kb = 0; kb < 4; kb++)
    aq[kb] = *(const bf16x8*)(Wqk + (size_t)l15 * 128 + kb * 32 + quad * 8);
  #pragma unroll
  for (int tile = 0; tile < 2; tile++) {
    f32x4 s = {};
    #pragma unroll
    for (int kb = 0; kb < 4; kb++)
      s = __builtin_amdgcn_mfma_f32_16x16x32_bf16(aq[kb], bx[tile][kb], s, 0, 0, 0);
    int node = node0 + tile * 16 + l15;
    if (node < M) {
      float4 v = {s[0], s[1], s[2], s[3]};
      *(float4*)(stbl + (size_t)node * 16 + quad * 4) = v;
    }
  }
}

// ------------- fused softmax + pooled gather + output GEMM -----------------
// h[t] = relu( sum_r ( sum_{e in (t,r)} w_e x[src_e] ) @ W_r + b ).
// Block = 512 thr = 8 waves, 16 targets (2/wave). Per target:
//   phase A (wave-wide): softmax weights into s_w/s_pk (deg<=64 fast path).
//   phase B (lane-split): group g8=lane>>3 owns relation g8's run; lane8
//     covers channels [lane8*8, +8) and [64+lane8*8, +8) via 2 dwordx4/edge;
//     2-wide unroll inside the run; flush 2x ds_write_b128 into As[tl].
// All 8 relations pool concurrently; no atomics (one writer per (t,r) row).
// __syncthreads once; wave wv computes ct=wv tile (16 tgt x 16 ch, K=1024)
// with B-frags from L2-resident WsT (256 KB shared by all blocks).
// Fragment conventions (verified): A-frag m=lane&15, k=quad*8+j; B-frag
// n=lane&15, k=quad*8+j; C/D row=quad*4+reg, col=lane&15.

#define LDK 1032   // As row stride in bf16 (2064 B: 16B-aligned, banks spread)

#define ACCV(A_, W_, V_)                                              \
  A_[0] = __builtin_fmaf(W_, bfToF((ushort_t)(V_.x & 0xFFFF)), A_[0]); \
  A_[1] = __builtin_fmaf(W_, bfToF((ushort_t)(V_.x >> 16)),    A_[1]); \
  A_[2] = __builtin_fmaf(W_, bfToF((ushort_t)(V_.y & 0xFFFF)), A_[2]); \
  A_[3] = __builtin_fmaf(W_, bfToF((ushort_t)(V_.y >> 16)),    A_[3]); \
  A_[4] = __builtin_fmaf(W_, bfToF((ushort_t)(V_.z & 0xFFFF)), A_[4]); \
  A_[5] = __builtin_fmaf(W_, bfToF((ushort_t)(V_.z >> 16)),    A_[5]); \
  A_[6] = __builtin_fmaf(W_, bfToF((ushort_t)(V_.w & 0xFFFF)), A_[6]); \
  A_[7] = __builtin_fmaf(W_, bfToF((ushort_t)(V_.w >> 16)),    A_[7]);

__global__ __launch_bounds__(512, 4) void
k_fused3(const ushort_t* __restrict__ feat,  // [M][128] bf16 node feats
         const float* __restrict__ stbl,     // [M][16]: 0..7 q-side, 8..15 k-side
         const int* __restrict__ rp2,        // [M*8+1]
         const int* __restrict__ sorted,     // src | (rel<<16), rel-sorted per t
         const ushort_t* __restrict__ WsT,   // [8][128][128] this layer
         const float* __restrict__ bias,
         ushort_t* __restrict__ h,           // [M][128] bf16 out
         int M) {
  __shared__ __align__(16) ushort_t As[16 * LDK];   // 33 KB
  __shared__ int   s_pk[8][64];
  __shared__ float s_w[8][64];
  int tid = threadIdx.x, wv = tid >> 6, lane = tid & 63;
  int l15 = lane & 15, quad = lane >> 4;
  int g8 = lane >> 3, lane8 = lane & 7;
  int t0 = blockIdx.x * 16;
  const uint4* fx4 = (const uint4*)feat;            // node row = 16 uint4

  for (int sub = 0; sub < 2; sub++) {
    int tl = wv * 2 + sub;                          // local target 0..15
    int t = t0 + tl;
    ushort_t* arow = As + (size_t)tl * LDK;
    if (t < M) {
      int e0 = rp2[t * 8], e1 = rp2[t * 8 + 8];
      int deg = e1 - e0;
      float m = -INFINITY, inv = 0.f;
      bool fast = (deg <= 64);

      // ---- phase A: softmax weights (wave-wide) ----
      if (fast) {
        float alpha = -INFINITY;
        int pk = 0;
        if (lane < deg) {
          pk = sorted[e0 + lane];
          int s = pk & 0xFFFF, r = pk >> 16;
          float a = stbl[(size_t)t * 16 + r] + stbl[(size_t)s * 16 + 8 + r];
          alpha = (a >= 0.f) ? a : 0.2f * a;        // leaky_relu 0.2
        }
        m = alpha;
        #pragma unroll
        for (int off = 32; off; off >>= 1) m = fmaxf(m, __shfl_xor(m, off, 64));
        float w = (lane < deg) ? __expf(alpha - m) : 0.f;
        float den = w;
        #pragma unroll
        for (int off = 32; off; off >>= 1) den += __shfl_xor(den, off, 64);
        inv = 1.f / (den + 1e-16f);
        s_pk[wv][lane] = pk;
        s_w[wv][lane] = w * inv;
      } else {
        float den = 0.f;
        for (int base = e0; base < e1; base += 64) {
          int cnt = min(64, e1 - base);
          float alpha = -INFINITY;
          if (lane < cnt) {
            int pk = sorted[base + lane];
            int s = pk & 0xFFFF, r = pk >> 16;
            float a = stbl[(size_t)t * 16 + r] + stbl[(size_t)s * 16 + 8 + r];
            alpha = (a >= 0.f) ? a : 0.2f * a;
          }
          float cm = alpha;
          #pragma unroll
          for (int off = 32; off; off >>= 1) cm = fmaxf(cm, __shfl_xor(cm, off, 64));
          float nm = fmaxf(m, cm);
          float w = (lane < cnt) ? __expf(alpha - nm) : 0.f;
          float ws = w;
          #pragma unroll
          for (int off = 32; off; off >>= 1) ws += __shfl_xor(ws, off, 64);
          den = den * __expf(m - nm) + ws;
          m = nm;
        }
        inv = 1.f / (den + 1e-16f);
      }

      // ---- phase B: group g8 pools relation g8's run ----
      int rs = rp2[t * 8 + g8], re = rp2[t * 8 + g8 + 1];
      float acc[16] = {};
      if (fast) {
        int i = rs - e0, iend = re - e0;
        for (; i + 1 < iend; i += 2) {              // 4 gathers in flight/group
          int p0 = s_pk[wv][i] & 0xFFFF;
          int p1 = s_pk[wv][i + 1] & 0xFFFF;
          float w0 = s_w[wv][i], w1 = s_w[wv][i + 1];
          uint4 a0 = fx4[(size_t)p0 * 16 + lane8];
          uint4 b0 = fx4[(size_t)p0 * 16 + 8 + lane8];
          uint4 a1 = fx4[(size_t)p1 * 16 + lane8];
          uint4 b1 = fx4[(size_t)p1 * 16 + 8 + lane8];
          ACCV(acc, w0, a0) ACCV((acc + 8), w0, b0)
          ACCV(acc, w1, a1) ACCV((acc + 8), w1, b1)
        }
        if (i < iend) {
          int p = s_pk[wv][i] & 0xFFFF;
          float w = s_w[wv][i];
          uint4 a = fx4[(size_t)p * 16 + lane8];
          uint4 b = fx4[(size_t)p * 16 + 8 + lane8];
          ACCV(acc, w, a) ACCV((acc + 8), w, b)
        }
      } else {
        for (int e = rs; e < re; e++) {
          int pk = sorted[e];
          int s = pk & 0xFFFF;
          float a = stbl[(size_t)t * 16 + g8] + stbl[(size_t)s * 16 + 8 + g8];
          a = (a >= 0.f) ? a : 0.2f * a;
          float w = __expf(a - m) * inv;
          uint4 va = fx4[(size_t)s * 16 + lane8];
          uint4 vb = fx4[(size_t)s * 16 + 8 + lane8];
          ACCV(acc, w, va) ACCV((acc + 8), w, vb)
        }
      }
      // flush: channels [lane8*8, +8) and [64+lane8*8, +8) of row (tl, r=g8)
      uint4 o0 = {packBf(acc[0], acc[1]), packBf(acc[2], acc[3]),
                  packBf(acc[4], acc[5]), packBf(acc[6], acc[7])};
      uint4 o1 = {packBf(acc[8], acc[9]), packBf(acc[10], acc[11]),
                  packBf(acc[12], acc[13]), packBf(acc[14], acc[15])};
      *(uint4*)(arow + g8 * 128 + lane8 * 8) = o0;
      *(uint4*)(arow + g8 * 128 + 64 + lane8 * 8) = o1;
    } else {
      uint4 z = {0, 0, 0, 0};
      *(uint4*)(arow + g8 * 128 + lane8 * 8) = z;
      *(uint4*)(arow + g8 * 128 + 64 + lane8 * 8) = z;
    }
  }
  __syncthreads();

  // ---- GEMM: wave wv computes ct = wv (16 targets x 16 cols), K = 1024 ----
  f32x4 dacc = {};
  #pragma unroll
  for (int r = 0; r < 8; r++) {
    const ushort_t* Wr = WsT + (size_t)r * 16384 + (size_t)(wv * 16 + l15) * 128;
    #pragma unroll
    for (int kb = 0; kb < 4; kb++) {
      bf16x8 afr = *(const bf16x8*)(As + (size_t)l15 * LDK + r * 128 + kb * 32 + quad * 8);
      bf16x8 bfr = *(const bf16x8*)(Wr + kb * 32 + quad * 8);
      dacc = __builtin_amdgcn_mfma_f32_16x16x32_bf16(afr, bfr, dacc, 0, 0, 0);
    }
  }

  // ---- epilogue: bias + relu -> bf16 ----
  float b = bias[wv * 16 + l15];
  #pragma unroll
  for (int reg = 0; reg < 4; reg++) {
    int rr = t0 + quad * 4 + reg;
    if (rr < M)
      h[(size_t)rr * 128 + wv * 16 + l15] = fToBf(fmaxf(dacc[reg] + b, 0.f));
  }
}

// ----------------------------- final linear --------------------------------

#define LDA 136

__global__ __launch_bounds__(256) void
k_gemmL(const ushort_t* __restrict__ A, const float* __restrict__ Wl,
        float* __restrict__ Cout, const float* __restrict__ bias, int M) {
  __shared__ ushort_t As[64 * LDA];
  __shared__ ushort_t Bs[128 * LDA];
  int tid = threadIdx.x;
  int row0 = blockIdx.x * 64;
  for (int c = tid; c < 1024; c += 256) {
    int r = c >> 4, off = (c & 15) * 8;
    int4 v = {0, 0, 0, 0};
    if (row0 + r < M) v = *(const int4*)(A + (size_t)(row0 + r) * 128 + off);
    *(int4*)(As + r * LDA + off) = v;
  }
  for (int c = tid; c < 2048; c += 256) {
    int nn = c >> 4, off = (c & 15) * 8;
    float4 a = *(const float4*)(Wl + (size_t)nn * 128 + off);
    float4 b = *(const float4*)(Wl + (size_t)nn * 128 + off + 4);
    ushort_t* d = Bs + nn * LDA + off;
    d[0] = fToBf(a.x); d[1] = fToBf(a.y); d[2] = fToBf(a.z); d[3] = fToBf(a.w);
    d[4] = fToBf(b.x); d[5] = fToBf(b.y); d[6] = fToBf(b.z); d[7] = fToBf(b.w);
  }
  __syncthreads();
  int wv = tid >> 6, lane = tid & 63;
  int l15 = lane & 15, quad = lane >> 4;
  int wr = wv * 16;
  bf16x8 afr[4];
  #pragma unroll
  for (int kb = 0; kb < 4; kb++)
    afr[kb] = *reinterpret_cast<const bf16x8*>(As + (wr + l15) * LDA + kb * 32 + quad * 8);
  f32x4 acc[8] = {};
  #pragma unroll
  for (int ct = 0; ct < 8; ct++)
    #pragma unroll
    for (int kb = 0; kb < 4; kb++) {
      bf16x8 bfr = *reinterpret_cast<const bf16x8*>(Bs + (ct * 16 + l15) * LDA + kb * 32 + quad * 8);
      acc[ct] = __builtin_amdgcn_mfma_f32_16x16x32_bf16(afr[kb], bfr, acc[ct], 0, 0, 0);
    }
  #pragma unroll
  for (int ct = 0; ct < 8; ct++)
    #pragma unroll
    for (int reg = 0; reg < 4; reg++) {
      int rr = row0 + wr + quad * 4 + reg;
      if (rr < M) Cout[(size_t)rr * 128 + ct * 16 + l15] = acc[ct][reg] + bias[ct * 16 + l15];
    }
}

// ------------------------------- launcher ----------------------------------

extern "C" void kernel_launch(void* const* d_in, const int* in_sizes, int n_in,
                              void* d_out, int out_size, void* d_ws, size_t ws_size,
                              hipStream_t stream) {
  const float* x   = (const float*)d_in[0];
  const int* ei    = (const int*)d_in[1];
  const int* etype = (const int*)d_in[2];
  const float* W1  = (const float*)d_in[4];
  const float* q1  = (const float*)d_in[5];
  const float* k1  = (const float*)d_in[6];
  const float* b1  = (const float*)d_in[7];
  const float* W2  = (const float*)d_in[8];
  const float* q2  = (const float*)d_in[9];
  const float* k2  = (const float*)d_in[10];
  const float* b2  = (const float*)d_in[11];
  const float* Wl  = (const float*)d_in[12];
  const float* bl  = (const float*)d_in[13];
  float* out       = (float*)d_out;

  const int N = in_sizes[0] / 128;   // 50000
  const int E = in_sizes[2];         // 800000

  char* ws = (char*)d_ws;
  size_t off = 0;
  auto alloc = [&](size_t bytes) {
    size_t o = off;
    off = (off + bytes + 255) & ~(size_t)255;
    return o;
  };

  ushort_t* h1    = (ushort_t*)(ws + alloc((size_t)N * 128 * 2));
  ushort_t* xbh2  = (ushort_t*)(ws + alloc((size_t)N * 128 * 2));    // xb then h2
  ushort_t* WsT   = (ushort_t*)(ws + alloc((size_t)2 * 8 * 16384 * 2));
  ushort_t* wqk   = (ushort_t*)(ws + alloc(2 * 16 * 128 * 2));
  float* stbl     = (float*)(ws + alloc((size_t)N * 16 * 4));
  int* deg2       = (int*)(ws + alloc((size_t)N * 8 * 4));
  int* cursor2    = (int*)(ws + alloc((size_t)N * 8 * 4));
  int* incl2      = (int*)(ws + alloc((size_t)N * 8 * 4));
  int* rowptr2    = (int*)(ws + alloc((size_t)(N * 8 + 1) * 4));
  int* bsum       = (int*)(ws + alloc(2048 * 4));
  int* sorted     = (int*)(ws + alloc((size_t)E * 4));
  (void)ws_size; (void)n_in; (void)out_size;

  const int* srcp = ei;
  const int* tgtp = ei + E;

  int n2 = N * 8;                    // 400000 segments
  int gE  = (E + 255) / 256;
  int gN2 = (n2 + 255) / 256;        // 1563
  int gS  = (N + 127) / 128;         // k_score: 391
  int gF  = (N + 15) / 16;           // k_fused3: 3125 (512-thr blocks)
  int gL  = (N + 63) / 64;           // k_gemmL: 782

  // CSR build on (target, relation) segments (once; same graph both layers)
  hipMemsetAsync(deg2, 0, (size_t)n2 * 4, stream);
  hipMemsetAsync(cursor2, 0, (size_t)n2 * 4, stream);
  k_count2<<<gE, 256, 0, stream>>>(tgtp, etype, deg2, E);
  k_scanA<<<gN2, 256, 0, stream>>>(deg2, incl2, bsum, n2);
  k_scanB2<<<1, 256, 0, stream>>>(bsum, gN2);
  k_scanC<<<gN2, 256, 0, stream>>>(deg2, incl2, bsum, rowptr2, n2, E);
  k_scatter2<<<gE, 256, 0, stream>>>(srcp, tgtp, etype, rowptr2, cursor2, sorted, E);

  // weight prep (both layers)
  k_wsT<<<1024, 256, 0, stream>>>(W1, W2, WsT);
  k_wqwk<<<16, 256, 0, stream>>>(W1, q1, k1, W2, q2, k2, wqk);

  // layer 1
  k_score<true><<<gS, 256, 0, stream>>>(x, wqk, xbh2, stbl, N);
  k_fused3<<<gF, 512, 0, stream>>>(xbh2, stbl, rowptr2, sorted, WsT, b1, h1, N);

  // layer 2 (xb buffer is dead after fused1; reused as h2 below)
  k_score<false><<<gS, 256, 0, stream>>>(h1, wqk + 2048, nullptr, stbl, N);
  k_fused3<<<gF, 512, 0, stream>>>(h1, stbl, rowptr2, sorted,
                                   WsT + (size_t)8 * 16384, b2, xbh2, N);

  // final linear
  k_gemmL<<<gL, 256, 0, stream>>>(xbh2, Wl, out, bl, N);
}

// Round 7
// 479.668 us; speedup vs baseline: 1.4896x; 1.0347x over previous
//
#include <hip/hip_runtime.h>

// ---------------------------------------------------------------------------
// RGAT encoder: N=50000, E=800000, R=8, IN=H=128, B=10.
// R15: R11 pipeline (score -> gather -> out GEMM) with the gather rebuilt:
//      - R14 lesson: 8-lanes-per-row loads = 8-line scatter per instr (slow).
//        Coalesced shape restored: 16 lanes x 16B cover one 256 B row; one
//        dwordx4 instr loads 4 complete edge rows (4 groups of 16 lanes).
//      - Per-relation accumulation in LDS f32 gacc[8][132] (pad 132 -> rows
//        on distinct bank phases; 16-lane b128 RMW conflict-free), 4-step
//        group-serialized RMW (relation-sorted => same-r edges adjacent).
//      - Wave per target, ~19 KB LDS/block -> full occupancy, 50k waves.
//      Launch trims: wsT+wqwk merged into k_prep; scanC emits scatter cursor
//      (cursor memset + rowptr add removed). k_out / k_gemmL from R11.
// ---------------------------------------------------------------------------

typedef unsigned int uint;
typedef unsigned short ushort_t;

using bf16x8 = __attribute__((ext_vector_type(8))) __bf16;
using f32x4  = __attribute__((ext_vector_type(4))) float;

__device__ __forceinline__ ushort_t fToBf(float f) {
  uint u = __float_as_uint(f);
  u += 0x7FFFu + ((u >> 16) & 1);   // round-to-nearest-even
  return (ushort_t)(u >> 16);
}
__device__ __forceinline__ float bfToF(ushort_t h) {
  return __uint_as_float(((uint)h) << 16);
}
__device__ __forceinline__ uint packBf(float a, float b) {
  return (uint)fToBf(a) | ((uint)fToBf(b) << 16);
}

// ------------------------------- CSR build ---------------------------------
// Segments keyed on t8r = tgt*8 + rel (400k segments); within a target the 8
// relation runs are contiguous ascending; softmax segment = [t*8, t*8+8).

__global__ void k_count2(const int* __restrict__ tgt, const int* __restrict__ et,
                         int* __restrict__ deg2, int E) {
  int e = blockIdx.x * 256 + threadIdx.x;
  if (e < E) atomicAdd(&deg2[tgt[e] * 8 + et[e]], 1);
}

__global__ void k_scanA(const int* __restrict__ deg, int* __restrict__ incl,
                        int* __restrict__ bsum, int n) {
  __shared__ int s[256];
  int tid = threadIdx.x;
  int i = blockIdx.x * 256 + tid;
  int v = (i < n) ? deg[i] : 0;
  s[tid] = v;
  __syncthreads();
  for (int off = 1; off < 256; off <<= 1) {
    int t = (tid >= off) ? s[tid - off] : 0;
    __syncthreads();
    s[tid] += t;
    __syncthreads();
  }
  if (i < n) incl[i] = s[tid];
  if (tid == 255) bsum[blockIdx.x] = s[255];
}

// single-block chunked exclusive scan of bsum[nb]
__global__ void k_scanB2(int* __restrict__ bsum, int nb) {
  __shared__ int s[256];
  __shared__ int carry;
  int tid = threadIdx.x;
  if (tid == 0) carry = 0;
  __syncthreads();
  for (int base = 0; base < nb; base += 256) {
    int i = base + tid;
    int v = (i < nb) ? bsum[i] : 0;
    s[tid] = v;
    __syncthreads();
    for (int off = 1; off < 256; off <<= 1) {
      int t = (tid >= off) ? s[tid - off] : 0;
      __syncthreads();
      s[tid] += t;
      __syncthreads();
    }
    int c = carry;
    if (i < nb) bsum[i] = c + s[tid] - v;   // exclusive
    __syncthreads();
    if (tid == 255) carry = c + s[255];
    __syncthreads();
  }
}

// writes rowptr AND the scatter cursor copy (absolute positions)
__global__ void k_scanC(const int* __restrict__ deg, const int* __restrict__ incl,
                        const int* __restrict__ bsum, int* __restrict__ rowptr,
                        int* __restrict__ cur, int n, int E) {
  int i = blockIdx.x * 256 + threadIdx.x;
  if (i < n) {
    int v = bsum[blockIdx.x] + incl[i] - deg[i];
    rowptr[i] = v;
    cur[i] = v;
    if (i == n - 1) rowptr[n] = E;
  }
}

__global__ void k_scatter2(const int* __restrict__ src, const int* __restrict__ tgt,
                           const int* __restrict__ et, int* __restrict__ cur,
                           int* __restrict__ sorted, int E) {
  int e = blockIdx.x * 256 + threadIdx.x;
  if (e >= E) return;
  int t8r = tgt[e] * 8 + et[e];
  int pos = atomicAdd(&cur[t8r], 1);        // absolute slot
  sorted[pos] = src[e] | (et[e] << 16);     // src < 65536, rel < 8
}

// ------------------------------ weight prep --------------------------------
// Merged: blocks 0..1023 build WsT[layer][r][n][k] = W[r][k][n] (B-frag rows);
// blocks 1024..1039 build wqk[layer][16][128] (rows 0..7 Wq[r], 8..15 Wk[r]).

__global__ void k_prep(const float* __restrict__ W1, const float* __restrict__ q1,
                       const float* __restrict__ k1, const float* __restrict__ W2,
                       const float* __restrict__ q2, const float* __restrict__ k2,
                       ushort_t* __restrict__ WsT, ushort_t* __restrict__ wqk) {
  int b = blockIdx.x;
  if (b < 1024) {
    int idx = b * 256 + threadIdx.x;           // ((l*8+r)*128 + k)*128 + n
    int n = idx & 127;
    int k = (idx >> 7) & 127;
    int rl = idx >> 14;                        // l*8 + r
    const float* W = (rl >> 3) ? W2 : W1;
    int r = rl & 7;
    float v = W[((size_t)r * 128 + k) * 128 + n];
    WsT[((size_t)rl * 128 + n) * 128 + k] = fToBf(v);
  } else {
    int g = (b - 1024) * 256 + threadIdx.x;    // 0..4095
    int layer = g >> 11;
    int which = (g >> 10) & 1;
    int idx = g & 1023;                        // r*128 + kin
    const float* w = (layer ? W2 : W1) + (size_t)idx * 128;
    const float* v = layer ? (which ? k2 : q2) : (which ? k1 : q1);
    float s = 0.f;
    #pragma unroll 8
    for (int hh = 0; hh < 128; hh++) s += w[hh] * v[hh];
    int r = idx >> 7, kin = idx & 127;
    wqk[(size_t)layer * 2048 + ((which << 3) + r) * 128 + kin] = fToBf(s);
  }
}

// ------------------------------- score pass --------------------------------
// stbl[node][16] = x[node] @ Wqk^T. F32IN additionally emits xb (bf16 cast).
// Fragment conventions (verified): A-frag m=lane&15, k=quad*8+j; B-frag
// n=lane&15, k=quad*8+j; C/D row=quad*4+reg, col=lane&15.

template <bool F32IN>
__global__ __launch_bounds__(256) void
k_score(const void* __restrict__ Ain,       // [M][128] f32 or bf16 node feats
        const ushort_t* __restrict__ Wqk,   // [16][128] this layer
        ushort_t* __restrict__ xb,          // [M][128] bf16 out (F32IN only)
        float* __restrict__ stbl,           // [M][16] out
        int M) {
  int tid = threadIdx.x, wv = tid >> 6, lane = tid & 63;
  int l15 = lane & 15, quad = lane >> 4;
  int node0 = blockIdx.x * 128 + wv * 32;

  bf16x8 bx[2][4];
  #pragma unroll
  for (int tile = 0; tile < 2; tile++) {
    int node = node0 + tile * 16 + l15;
    int nc = node < M ? node : M - 1;
    if (F32IN) {
      const float* row = (const float*)Ain + (size_t)nc * 128;
      #pragma unroll
      for (int kb = 0; kb < 4; kb++) {
        float4 a = *(const float4*)(row + kb * 32 + quad * 8);
        float4 b = *(const float4*)(row + kb * 32 + quad * 8 + 4);
        union { bf16x8 v; ushort_t u[8]; } t;
        t.u[0] = fToBf(a.x); t.u[1] = fToBf(a.y); t.u[2] = fToBf(a.z); t.u[3] = fToBf(a.w);
        t.u[4] = fToBf(b.x); t.u[5] = fToBf(b.y); t.u[6] = fToBf(b.z); t.u[7] = fToBf(b.w);
        bx[tile][kb] = t.v;
      }
    } else {
      const ushort_t* row = (const ushort_t*)Ain + (size_t)nc * 128;
      #pragma unroll
      for (int kb = 0; kb < 4; kb++)
        bx[tile][kb] = *(const bf16x8*)(row + kb * 32 + quad * 8);
    }
  }

  if (F32IN) {
    #pragma unroll
    for (int tile = 0; tile < 2; tile++) {
      int node = node0 + tile * 16 + l15;
      if (node < M) {
        #pragma unroll
        for (int kb = 0; kb < 4; kb++)
          *(bf16x8*)(xb + (size_t)node * 128 + kb * 32 + quad * 8) = bx[tile][kb];
      }
    }
  }

  bf16x8 aq[4];
  #pragma unroll
  for (int kb = 0; kb < 4; kb++)
    aq[kb] = *(const bf16x8*)(Wqk + (size_t)l15 * 128 + kb * 32 + quad * 8);
  #pragma unroll
  for (int tile = 0; tile < 2; tile++) {
    f32x4 s = {};
    #pragma unroll
    for (int kb = 0; kb < 4; kb++)
      s = __builtin_amdgcn_mfma_f32_16x16x32_bf16(aq[kb], bx[tile][kb], s, 0, 0, 0);
    int node = node0 + tile * 16 + l15;
    if (node < M) {
      float4 v = {s[0], s[1], s[2], s[3]};
      *(float4*)(stbl + (size_t)node * 16 + quad * 4) = v;
    }
  }
}

// ---------------- softmax + per-relation pooled gather ---------------------
// One wave per target. Phase A: softmax weights (m, den; deg<=64 fast path
// caches {pk, w/den} in LDS). Phase B: batches of 4 edges; ONE dwordx4 instr
// loads 4 complete 256 B rows (group g4 = 16 lanes owns edge base+g4, lane
// fcol covers channels [fcol*8, fcol*8+8)); RMW into gacc[8][132] f32,
// serialized over the 4 groups (same-r edges are adjacent -> races otherwise).
// Flush: 8 bf16 rows -> g[t][r][128]. gacc padded 132 -> bank-phase distinct.

__global__ __launch_bounds__(256) void
k_gather2(const ushort_t* __restrict__ feat,  // [n][128] bf16 node feats
          const float* __restrict__ stbl,     // [n][16]: 0..7 q, 8..15 k
          const int* __restrict__ rp2,        // [n*8+1]
          const int* __restrict__ sorted,     // src | (rel<<16), rel-sorted per t
          ushort_t* __restrict__ g,           // [n][8][128] bf16 out
          int n) {
  __shared__ float gacc[4][8 * 132];          // 16.9 KB
  __shared__ int   s_pk[4][64];
  __shared__ float s_w[4][64];
  int tid = threadIdx.x, wv = tid >> 6, lane = tid & 63;
  int g4 = lane >> 4, fcol = lane & 15;
  int t = blockIdx.x * 4 + wv;
  if (t >= n) return;

  float* gw = gacc[wv];
  for (int i = lane; i < 1056; i += 64) gw[i] = 0.f;

  int e0 = rp2[t * 8], e1 = rp2[t * 8 + 8];
  int deg = e1 - e0;
  float m = -INFINITY, inv = 0.f;
  bool fast = (deg <= 64);

  // ---- phase A: softmax ----
  if (fast) {
    float alpha = -INFINITY;
    int pk = 0;
    if (lane < deg) {
      pk = sorted[e0 + lane];
      int s = pk & 0xFFFF, r = pk >> 16;
      float a = stbl[(size_t)t * 16 + r] + stbl[(size_t)s * 16 + 8 + r];
      alpha = (a >= 0.f) ? a : 0.2f * a;      // leaky_relu 0.2
    }
    m = alpha;
    #pragma unroll
    for (int off = 32; off; off >>= 1) m = fmaxf(m, __shfl_xor(m, off, 64));
    float w = (lane < deg) ? __expf(alpha - m) : 0.f;
    float den = w;
    #pragma unroll
    for (int off = 32; off; off >>= 1) den += __shfl_xor(den, off, 64);
    inv = 1.f / (den + 1e-16f);
    s_pk[wv][lane] = (lane < deg) ? pk : 0;
    s_w[wv][lane] = w * inv;
  } else {
    float den = 0.f;
    for (int base = e0; base < e1; base += 64) {
      int cnt = min(64, e1 - base);
      float alpha = -INFINITY;
      if (lane < cnt) {
        int pk = sorted[base + lane];
        int s = pk & 0xFFFF, r = pk >> 16;
        float a = stbl[(size_t)t * 16 + r] + stbl[(size_t)s * 16 + 8 + r];
        alpha = (a >= 0.f) ? a : 0.2f * a;
      }
      float cm = alpha;
      #pragma unroll
      for (int off = 32; off; off >>= 1) cm = fmaxf(cm, __shfl_xor(cm, off, 64));
      float nm = fmaxf(m, cm);
      float w = (lane < cnt) ? __expf(alpha - nm) : 0.f;
      float ws = w;
      #pragma unroll
      for (int off = 32; off; off >>= 1) ws += __shfl_xor(ws, off, 64);
      den = den * __expf(m - nm) + ws;
      m = nm;
    }
    inv = 1.f / (den + 1e-16f);
  }

  // ---- phase B: batches of 4 edges, coalesced rows, LDS f32 RMW ----
  const uint4* fx4 = (const uint4*)feat;      // node row = 16 uint4
  for (int base = e0; base < e1; base += 4) {
    int i = base + g4;
    bool valid = (i < e1);
    int pk = 0;
    float w = 0.f;
    if (fast) {
      int li = i - e0;
      if (valid) {
        pk = s_pk[wv][li];
        w = s_w[wv][li];
      }
    } else if (valid) {
      pk = sorted[i];
      int s = pk & 0xFFFF, r = pk >> 16;
      float a = stbl[(size_t)t * 16 + r] + stbl[(size_t)s * 16 + 8 + r];
      a = (a >= 0.f) ? a : 0.2f * a;
      w = __expf(a - m) * inv;
    }
    int src = pk & 0xFFFF, r = pk >> 16;
    uint4 v = {0, 0, 0, 0};
    if (valid) v = fx4[(size_t)src * 16 + fcol];   // 4 full rows per instr
    float* row = gw + r * 132 + fcol * 8;
    #pragma unroll
    for (int s4 = 0; s4 < 4; s4++) {
      if (g4 == s4 && valid) {
        float4 c0 = *(float4*)row;
        float4 c1 = *(float4*)(row + 4);
        c0.x = __builtin_fmaf(w, bfToF((ushort_t)(v.x & 0xFFFF)), c0.x);
        c0.y = __builtin_fmaf(w, bfToF((ushort_t)(v.x >> 16)),    c0.y);
        c0.z = __builtin_fmaf(w, bfToF((ushort_t)(v.y & 0xFFFF)), c0.z);
        c0.w = __builtin_fmaf(w, bfToF((ushort_t)(v.y >> 16)),    c0.w);
        c1.x = __builtin_fmaf(w, bfToF((ushort_t)(v.z & 0xFFFF)), c1.x);
        c1.y = __builtin_fmaf(w, bfToF((ushort_t)(v.z >> 16)),    c1.y);
        c1.z = __builtin_fmaf(w, bfToF((ushort_t)(v.w & 0xFFFF)), c1.z);
        c1.w = __builtin_fmaf(w, bfToF((ushort_t)(v.w >> 16)),    c1.w);
        *(float4*)row = c0;
        *(float4*)(row + 4) = c1;
      }
    }
  }

  // ---- flush: 8 rows -> g[t][r][128] bf16 ----
  uint* gout = (uint*)(g + (size_t)t * 1024);
  #pragma unroll
  for (int r = 0; r < 8; r++) {
    float a = gw[r * 132 + lane * 2];
    float b = gw[r * 132 + lane * 2 + 1];
    gout[r * 64 + lane] = packBf(a, b);
  }
}

// --------------------- output GEMM: h = relu(g @ Wstack + b) ---------------
// A = g viewed as [M][K=1024] (relation-major row blocks), B = WsT chunks.

#define LDA 136

__global__ __launch_bounds__(256) void
k_out(const ushort_t* __restrict__ g,     // [M][8][128] bf16
      const ushort_t* __restrict__ WsT,   // [8][128][128] this layer
      const float* __restrict__ bias,
      ushort_t* __restrict__ h,           // [M][128] bf16 out (standard order)
      int M) {
  __shared__ ushort_t As[64 * LDA];
  __shared__ ushort_t Bs[128 * LDA];
  int tid = threadIdx.x, wv = tid >> 6, lane = tid & 63;
  int l15 = lane & 15, quad = lane >> 4;
  int row0 = blockIdx.x * 64;
  int wr = wv * 16;
  f32x4 acc[8] = {};

  for (int r = 0; r < 8; r++) {
    // stage As: 64 rows x 256 B of relation-r g rows
    {
      int row = tid >> 2, seg = tid & 3;
      int4 z = {0, 0, 0, 0};
      int4 v0 = z, v1 = z, v2 = z, v3 = z;
      if (row0 + row < M) {
        const int4* src = (const int4*)(g + ((size_t)(row0 + row) * 8 + r) * 128 + seg * 32);
        v0 = src[0]; v1 = src[1]; v2 = src[2]; v3 = src[3];
      }
      int4* dst = (int4*)(As + row * LDA + seg * 32);
      dst[0] = v0; dst[1] = v1; dst[2] = v2; dst[3] = v3;
    }
    // stage Bs: WsT[r] flat 32 KB ([n][k] rows)
    {
      const int4* src = (const int4*)(WsT + (size_t)r * 16384);
      for (int u = tid; u < 512; u += 256) {
        int rowb = u >> 2, seg = u & 3;
        int4* dst = (int4*)(Bs + rowb * LDA + seg * 32);
        #pragma unroll
        for (int j = 0; j < 4; j++) dst[j] = src[rowb * 16 + seg * 4 + j];
      }
    }
    __syncthreads();

    bf16x8 afr[4];
    #pragma unroll
    for (int kb = 0; kb < 4; kb++)
      afr[kb] = *(const bf16x8*)(As + (wr + l15) * LDA + kb * 32 + quad * 8);
    #pragma unroll
    for (int ct = 0; ct < 8; ct++)
      #pragma unroll
      for (int kb = 0; kb < 4; kb++) {
        bf16x8 bfr = *(const bf16x8*)(Bs + (ct * 16 + l15) * LDA + kb * 32 + quad * 8);
        acc[ct] = __builtin_amdgcn_mfma_f32_16x16x32_bf16(afr[kb], bfr, acc[ct], 0, 0, 0);
      }
    __syncthreads();
  }

  #pragma unroll
  for (int ct = 0; ct < 8; ct++) {
    float b = bias[ct * 16 + l15];
    #pragma unroll
    for (int reg = 0; reg < 4; reg++) {
      int rr = row0 + wr + quad * 4 + reg;
      if (rr < M)
        h[(size_t)rr * 128 + ct * 16 + l15] = fToBf(fmaxf(acc[ct][reg] + b, 0.f));
    }
  }
}

// ----------------------------- final linear --------------------------------

__global__ __launch_bounds__(256) void
k_gemmL(const ushort_t* __restrict__ A, const float* __restrict__ Wl,
        float* __restrict__ Cout, const float* __restrict__ bias, int M) {
  __shared__ ushort_t As[64 * LDA];
  __shared__ ushort_t Bs[128 * LDA];
  int tid = threadIdx.x;
  int row0 = blockIdx.x * 64;
  for (int c = tid; c < 1024; c += 256) {
    int r = c >> 4, off = (c & 15) * 8;
    int4 v = {0, 0, 0, 0};
    if (row0 + r < M) v = *(const int4*)(A + (size_t)(row0 + r) * 128 + off);
    *(int4*)(As + r * LDA + off) = v;
  }
  for (int c = tid; c < 2048; c += 256) {
    int nn = c >> 4, off = (c & 15) * 8;
    float4 a = *(const float4*)(Wl + (size_t)nn * 128 + off);
    float4 b = *(const float4*)(Wl + (size_t)nn * 128 + off + 4);
    ushort_t* d = Bs + nn * LDA + off;
    d[0] = fToBf(a.x); d[1] = fToBf(a.y); d[2] = fToBf(a.z); d[3] = fToBf(a.w);
    d[4] = fToBf(b.x); d[5] = fToBf(b.y); d[6] = fToBf(b.z); d[7] = fToBf(b.w);
  }
  __syncthreads();
  int wv = tid >> 6, lane = tid & 63;
  int l15 = lane & 15, quad = lane >> 4;
  int wr = wv * 16;
  bf16x8 afr[4];
  #pragma unroll
  for (int kb = 0; kb < 4; kb++)
    afr[kb] = *reinterpret_cast<const bf16x8*>(As + (wr + l15) * LDA + kb * 32 + quad * 8);
  f32x4 acc[8] = {};
  #pragma unroll
  for (int ct = 0; ct < 8; ct++)
    #pragma unroll
    for (int kb = 0; kb < 4; kb++) {
      bf16x8 bfr = *reinterpret_cast<const bf16x8*>(Bs + (ct * 16 + l15) * LDA + kb * 32 + quad * 8);
      acc[ct] = __builtin_amdgcn_mfma_f32_16x16x32_bf16(afr[kb], bfr, acc[ct], 0, 0, 0);
    }
  #pragma unroll
  for (int ct = 0; ct < 8; ct++)
    #pragma unroll
    for (int reg = 0; reg < 4; reg++) {
      int rr = row0 + wr + quad * 4 + reg;
      if (rr < M) Cout[(size_t)rr * 128 + ct * 16 + l15] = acc[ct][reg] + bias[ct * 16 + l15];
    }
}

// ------------------------------- launcher ----------------------------------

extern "C" void kernel_launch(void* const* d_in, const int* in_sizes, int n_in,
                              void* d_out, int out_size, void* d_ws, size_t ws_size,
                              hipStream_t stream) {
  const float* x   = (const float*)d_in[0];
  const int* ei    = (const int*)d_in[1];
  const int* etype = (const int*)d_in[2];
  const float* W1  = (const float*)d_in[4];
  const float* q1  = (const float*)d_in[5];
  const float* k1  = (const float*)d_in[6];
  const float* b1  = (const float*)d_in[7];
  const float* W2  = (const float*)d_in[8];
  const float* q2  = (const float*)d_in[9];
  const float* k2  = (const float*)d_in[10];
  const float* b2  = (const float*)d_in[11];
  const float* Wl  = (const float*)d_in[12];
  const float* bl  = (const float*)d_in[13];
  float* out       = (float*)d_out;

  const int N = in_sizes[0] / 128;   // 50000
  const int E = in_sizes[2];         // 800000

  char* ws = (char*)d_ws;
  size_t off = 0;
  auto alloc = [&](size_t bytes) {
    size_t o = off;
    off = (off + bytes + 255) & ~(size_t)255;
    return o;
  };

  ushort_t* g     = (ushort_t*)(ws + alloc((size_t)N * 1024 * 2));   // 102.4 MB
  ushort_t* h1    = (ushort_t*)(ws + alloc((size_t)N * 128 * 2));
  ushort_t* xbh2  = (ushort_t*)(ws + alloc((size_t)N * 128 * 2));    // xb then h2
  ushort_t* WsT   = (ushort_t*)(ws + alloc((size_t)2 * 8 * 16384 * 2));
  ushort_t* wqk   = (ushort_t*)(ws + alloc(2 * 16 * 128 * 2));
  float* stbl     = (float*)(ws + alloc((size_t)N * 16 * 4));
  int* deg2       = (int*)(ws + alloc((size_t)N * 8 * 4));
  int* cur2       = (int*)(ws + alloc((size_t)N * 8 * 4));
  int* incl2      = (int*)(ws + alloc((size_t)N * 8 * 4));
  int* rowptr2    = (int*)(ws + alloc((size_t)(N * 8 + 1) * 4));
  int* bsum       = (int*)(ws + alloc(2048 * 4));
  int* sorted     = (int*)(ws + alloc((size_t)E * 4));
  (void)ws_size; (void)n_in; (void)out_size;

  const int* srcp = ei;
  const int* tgtp = ei + E;

  int n2 = N * 8;                    // 400000 segments
  int gE  = (E + 255) / 256;
  int gN2 = (n2 + 255) / 256;        // 1563
  int gS  = (N + 127) / 128;         // k_score: 391
  int gG  = (N + 3) / 4;             // k_gather2: 12500
  int gO  = (N + 63) / 64;           // k_out / k_gemmL: 782

  // CSR build on (target, relation) segments (once; same graph both layers)
  hipMemsetAsync(deg2, 0, (size_t)n2 * 4, stream);
  k_count2<<<gE, 256, 0, stream>>>(tgtp, etype, deg2, E);
  k_scanA<<<gN2, 256, 0, stream>>>(deg2, incl2, bsum, n2);
  k_scanB2<<<1, 256, 0, stream>>>(bsum, gN2);
  k_scanC<<<gN2, 256, 0, stream>>>(deg2, incl2, bsum, rowptr2, cur2, n2, E);
  k_scatter2<<<gE, 256, 0, stream>>>(srcp, tgtp, etype, cur2, sorted, E);

  // weight prep (both layers, merged)
  k_prep<<<1040, 256, 0, stream>>>(W1, q1, k1, W2, q2, k2, WsT, wqk);

  // layer 1
  k_score<true><<<gS, 256, 0, stream>>>(x, wqk, xbh2, stbl, N);
  k_gather2<<<gG, 256, 0, stream>>>(xbh2, stbl, rowptr2, sorted, g, N);
  k_out<<<gO, 256, 0, stream>>>(g, WsT, b1, h1, N);

  // layer 2 (xb buffer is dead after gather1; reused as h2 below)
  k_score<false><<<gS, 256, 0, stream>>>(h1, wqk + 2048, nullptr, stbl, N);
  k_gather2<<<gG, 256, 0, stream>>>(h1, stbl, rowptr2, sorted, g, N);
  k_out<<<gO, 256, 0, stream>>>(g, WsT + (size_t)8 * 16384, b2, xbh2, N);

  // final linear
  k_gemmL<<<gO, 256, 0, stream>>>(xbh2, Wl, out, bl, N);
}